// Round 1
// baseline (861.170 us; speedup 1.0000x reference)
//
#include <hip/hip_runtime.h>
#include <hip/hip_bf16.h>

#define HID 128

// ---------------- degree / scan / csr ----------------
__global__ void k_degree(const int* __restrict__ dst, int* __restrict__ deg, int e) {
    int i = blockIdx.x * blockDim.x + threadIdx.x;
    if (i < e) atomicAdd(&deg[dst[i]], 1);
}

__global__ void k_scan1(const int* __restrict__ deg, int* __restrict__ offs,
                        int* __restrict__ part, int n) {
    __shared__ int s[256];
    int tid = threadIdx.x;
    int i = blockIdx.x * 256 + tid;
    int v = (i < n) ? deg[i] : 0;
    s[tid] = v; __syncthreads();
    for (int off = 1; off < 256; off <<= 1) {
        int t = (tid >= off) ? s[tid - off] : 0;
        __syncthreads();
        s[tid] += t;
        __syncthreads();
    }
    if (i < n) offs[i] = s[tid] - v;          // exclusive within block
    if (tid == 255) part[blockIdx.x] = s[255]; // block total
}

__global__ void k_scan2(int* __restrict__ part, int nb) {
    __shared__ int s[256];
    int tid = threadIdx.x;
    int v = (tid < nb) ? part[tid] : 0;
    s[tid] = v; __syncthreads();
    for (int off = 1; off < 256; off <<= 1) {
        int t = (tid >= off) ? s[tid - off] : 0;
        __syncthreads();
        s[tid] += t;
        __syncthreads();
    }
    part[tid] = s[tid] - v; // exclusive
}

__global__ void k_scan3(int* __restrict__ offs, const int* __restrict__ part, int n) {
    int i = blockIdx.x * 256 + threadIdx.x;
    if (i < n) offs[i] += part[blockIdx.x];
}

__global__ void k_dinv(const int* __restrict__ deg, float* __restrict__ dinv, int n) {
    int i = blockIdx.x * blockDim.x + threadIdx.x;
    if (i < n) dinv[i] = rsqrtf((float)(deg[i] + 1)); // +1 self loop, always > 0
}

__global__ void k_fill(const int* __restrict__ src, const int* __restrict__ dst,
                       const int* __restrict__ offs, int* __restrict__ cursor,
                       const float* __restrict__ dinv, int* __restrict__ csr,
                       float* __restrict__ csrw, int e) {
    int i = blockIdx.x * blockDim.x + threadIdx.x;
    if (i < e) {
        int s = src[i], d = dst[i];
        int p = offs[d] + atomicAdd(&cursor[d], 1);
        csr[p] = s;
        csrw[p] = dinv[s];
    }
}

// ---------------- layer 1: one-hot "GEMM" ----------------
__global__ void k_layer1(const int* __restrict__ res, const float* __restrict__ pos,
                         const float* __restrict__ W /*23x128*/, float* __restrict__ h, int n) {
    int t = blockIdx.x * blockDim.x + threadIdx.x;
    if (t >= n * HID) return;
    int i = t >> 7, c = t & 127;
    float v = W[res[i] * HID + c]
            + pos[i * 3 + 0] * W[20 * HID + c]
            + pos[i * 3 + 1] * W[21 * HID + c]
            + pos[i * 3 + 2] * W[22 * HID + c];
    h[t] = v;
}

// ---------------- pull aggregation (+bias+relu) ----------------
__global__ void k_agg(const float* __restrict__ h, const int* __restrict__ offs,
                      const int* __restrict__ cnt, const int* __restrict__ csr,
                      const float* __restrict__ csrw, const float* __restrict__ dinv,
                      const float* __restrict__ bias, float* __restrict__ out, int n) {
    int i = blockIdx.x;
    int c = threadIdx.x;
    float di = dinv[i];
    float acc = di * h[(size_t)i * HID + c]; // self loop: norm = di*di (outer di applied at end)
    int s0 = offs[i], m = cnt[i];
    for (int e = 0; e < m; ++e) {
        int s = csr[s0 + e];
        float w = csrw[s0 + e];
        acc += w * h[(size_t)s * HID + c];
    }
    float v = di * acc + bias[c];
    out[(size_t)i * HID + c] = v > 0.f ? v : 0.f;
}

// ---------------- fp32 tiled GEMM: C[n,128] = A[n,128] @ W[128,128] ----------------
__global__ __launch_bounds__(256) void k_gemm(const float* __restrict__ A,
                                              const float* __restrict__ W,
                                              float* __restrict__ C, int n) {
    __shared__ float As[32][68];   // [k][row], padded
    __shared__ float Ws[32][132];  // [k][col], padded
    const int tid = threadIdx.x;
    const int tx = tid & 15;   // col group (8 cols)
    const int ty = tid >> 4;   // row group (4 rows)
    const int r0 = blockIdx.x * 64;
    float acc[4][8] = {};
    for (int kk = 0; kk < HID; kk += 32) {
        {
            int kq = tid & 7, row = tid >> 3; // rows 0..31, then +32
            #pragma unroll
            for (int hh = 0; hh < 2; ++hh, row += 32) {
                int gr = r0 + row;
                float4 a = (gr < n) ? *(const float4*)&A[(size_t)gr * HID + kk + kq * 4]
                                    : make_float4(0.f, 0.f, 0.f, 0.f);
                As[kq * 4 + 0][row] = a.x; As[kq * 4 + 1][row] = a.y;
                As[kq * 4 + 2][row] = a.z; As[kq * 4 + 3][row] = a.w;
            }
        }
        {
            int cq = tid & 31, kr = tid >> 5; // kr 0..7, then +8 x4
            #pragma unroll
            for (int hh = 0; hh < 4; ++hh, kr += 8)
                *(float4*)&Ws[kr][cq * 4] = *(const float4*)&W[(size_t)(kk + kr) * HID + cq * 4];
        }
        __syncthreads();
        #pragma unroll
        for (int k = 0; k < 32; ++k) {
            float4 a  = *(const float4*)&As[k][ty * 4];
            float4 w0 = *(const float4*)&Ws[k][tx * 8];
            float4 w1 = *(const float4*)&Ws[k][tx * 8 + 4];
            float av[4] = {a.x, a.y, a.z, a.w};
            float wv[8] = {w0.x, w0.y, w0.z, w0.w, w1.x, w1.y, w1.z, w1.w};
            #pragma unroll
            for (int r = 0; r < 4; ++r)
                #pragma unroll
                for (int c = 0; c < 8; ++c) acc[r][c] += av[r] * wv[c];
        }
        __syncthreads();
    }
    #pragma unroll
    for (int r = 0; r < 4; ++r) {
        int gr = r0 + ty * 4 + r;
        if (gr < n) {
            *(float4*)&C[(size_t)gr * HID + tx * 8]     = make_float4(acc[r][0], acc[r][1], acc[r][2], acc[r][3]);
            *(float4*)&C[(size_t)gr * HID + tx * 8 + 4] = make_float4(acc[r][4], acc[r][5], acc[r][6], acc[r][7]);
        }
    }
}

// ---------------- mean pool (sorted batch, run-length + atomics) ----------------
__global__ void k_pool(const float* __restrict__ x, const int* __restrict__ batch,
                       float* __restrict__ pool, int* __restrict__ cnt, int n) {
    const int ROWS = 512;
    int start = blockIdx.x * ROWS;
    int end = start + ROWS; if (end > n) end = n;
    int c = threadIdx.x;
    float acc = 0.f;
    int cur = batch[start];
    int run = 0;
    for (int r = start; r < end; ++r) {
        int b = batch[r];
        if (b != cur) {
            atomicAdd(&pool[cur * HID + c], acc);
            if (c == 0) atomicAdd(&cnt[cur], run);
            acc = 0.f; run = 0; cur = b;
        }
        acc += x[(size_t)r * HID + c];
        run++;
    }
    atomicAdd(&pool[cur * HID + c], acc);
    if (c == 0) atomicAdd(&cnt[cur], run);
}

__global__ void k_pool_div(float* __restrict__ pool, const int* __restrict__ cnt) {
    int b = blockIdx.x, c = threadIdx.x;
    float d = (float)cnt[b]; if (d < 1.f) d = 1.f;
    pool[b * HID + c] /= d;
}

// ---------------- timestep embedding ----------------
__global__ void k_temb(const int* __restrict__ t, const float* __restrict__ Wt1,
                       const float* __restrict__ bt1, const float* __restrict__ Wt2,
                       const float* __restrict__ bt2, float* __restrict__ te) {
    __shared__ float hs[HID];
    int b = blockIdx.x, c = threadIdx.x;
    float tv = (float)t[b];
    float hv = tv * Wt1[c] + bt1[c];
    hs[c] = hv > 0.f ? hv : 0.f;
    __syncthreads();
    float s = bt2[c];
    for (int k = 0; k < HID; ++k) s += hs[k] * Wt2[k * HID + c];
    te[b * HID + c] = s;
}

// ---------------- combo[b] = pe[b]@Wn1[128:256] + te[b]@Wn1[256:384] + bn1 ----------------
__global__ void k_combo(const float* __restrict__ pe, const float* __restrict__ te,
                        const float* __restrict__ Wn1, const float* __restrict__ bn1,
                        float* __restrict__ combo) {
    int b = blockIdx.x, c = threadIdx.x;
    const float* Wp = Wn1 + 128 * HID;
    const float* Wt = Wn1 + 256 * HID;
    float s = bn1[c];
    for (int k = 0; k < HID; ++k)
        s += pe[b * HID + k] * Wp[k * HID + c] + te[b * HID + k] * Wt[k * HID + c];
    combo[b * HID + c] = s;
}

// ---------------- fused final head ----------------
__global__ __launch_bounds__(256) void k_final(const float* __restrict__ A /*x_m*/,
        const float* __restrict__ Wn1, const float* __restrict__ combo,
        const int* __restrict__ mbatch, const float* __restrict__ noisy,
        const float* __restrict__ Wn2, const float* __restrict__ bn2,
        float* __restrict__ out, int n) {
    __shared__ float As[32][68];
    __shared__ float Ws[32][132];
    __shared__ float hsm[64][133];
    const int tid = threadIdx.x;
    const int tx = tid & 15;
    const int ty = tid >> 4;
    const int r0 = blockIdx.x * 64;
    float acc[4][8] = {};
    for (int kk = 0; kk < HID; kk += 32) {
        {
            int kq = tid & 7, row = tid >> 3;
            #pragma unroll
            for (int hh = 0; hh < 2; ++hh, row += 32) {
                int gr = r0 + row;
                float4 a = (gr < n) ? *(const float4*)&A[(size_t)gr * HID + kk + kq * 4]
                                    : make_float4(0.f, 0.f, 0.f, 0.f);
                As[kq * 4 + 0][row] = a.x; As[kq * 4 + 1][row] = a.y;
                As[kq * 4 + 2][row] = a.z; As[kq * 4 + 3][row] = a.w;
            }
        }
        {
            int cq = tid & 31, kr = tid >> 5;
            #pragma unroll
            for (int hh = 0; hh < 4; ++hh, kr += 8)
                *(float4*)&Ws[kr][cq * 4] = *(const float4*)&Wn1[(size_t)(kk + kr) * HID + cq * 4];
        }
        __syncthreads();
        #pragma unroll
        for (int k = 0; k < 32; ++k) {
            float4 a  = *(const float4*)&As[k][ty * 4];
            float4 w0 = *(const float4*)&Ws[k][tx * 8];
            float4 w1 = *(const float4*)&Ws[k][tx * 8 + 4];
            float av[4] = {a.x, a.y, a.z, a.w};
            float wv[8] = {w0.x, w0.y, w0.z, w0.w, w1.x, w1.y, w1.z, w1.w};
            #pragma unroll
            for (int r = 0; r < 4; ++r)
                #pragma unroll
                for (int c = 0; c < 8; ++c) acc[r][c] += av[r] * wv[c];
        }
        __syncthreads();
    }
    // epilogue: + noisy@Wn1[384:387] + combo[batch], relu -> hidden in LDS
    const float* Wna = Wn1 + 384 * HID;
    #pragma unroll
    for (int r = 0; r < 4; ++r) {
        int lr = ty * 4 + r;
        int gr = r0 + lr;
        if (gr < n) {
            int b = mbatch[gr];
            float na0 = noisy[gr * 3 + 0], na1 = noisy[gr * 3 + 1], na2 = noisy[gr * 3 + 2];
            #pragma unroll
            for (int c = 0; c < 8; ++c) {
                int col = tx * 8 + c;
                float v = acc[r][c]
                        + na0 * Wna[col] + na1 * Wna[HID + col] + na2 * Wna[2 * HID + col]
                        + combo[b * HID + col];
                hsm[lr][col] = v > 0.f ? v : 0.f;
            }
        }
    }
    __syncthreads();
    // out[row, j] = hidden[row] . Wn2[:, j] + bn2[j]
    if (tid < 192) {
        int lr = tid / 3, j = tid - lr * 3;
        int gr = r0 + lr;
        if (gr < n) {
            float s = bn2[j];
            for (int c = 0; c < HID; ++c) s += hsm[lr][c] * Wn2[c * 3 + j];
            out[(size_t)gr * 3 + j] = s;
        }
    }
}

// ---------------- host ----------------
extern "C" void kernel_launch(void* const* d_in, const int* in_sizes, int n_in,
                              void* d_out, int out_size, void* d_ws, size_t ws_size,
                              hipStream_t stream) {
    const int*   p_res  = (const int*)d_in[0];
    const float* p_pos  = (const float*)d_in[1];
    const int*   p_ei   = (const int*)d_in[2];
    const int*   p_bat  = (const int*)d_in[3];
    const int*   m_res  = (const int*)d_in[4];
    const float* m_pos  = (const float*)d_in[5];
    const int*   m_ei   = (const int*)d_in[6];
    const int*   m_bat  = (const int*)d_in[7];
    const int*   t      = (const int*)d_in[8];
    const float* noisy  = (const float*)d_in[9];
    const float* Wp1 = (const float*)d_in[10], *bp1 = (const float*)d_in[11];
    const float* Wp2 = (const float*)d_in[12], *bp2 = (const float*)d_in[13];
    const float* Wm1 = (const float*)d_in[14], *bm1 = (const float*)d_in[15];
    const float* Wm2 = (const float*)d_in[16], *bm2 = (const float*)d_in[17];
    const float* Wt1 = (const float*)d_in[18], *bt1 = (const float*)d_in[19];
    const float* Wt2 = (const float*)d_in[20], *bt2 = (const float*)d_in[21];
    const float* Wn1 = (const float*)d_in[22], *bn1 = (const float*)d_in[23];
    const float* Wn2 = (const float*)d_in[24], *bn2 = (const float*)d_in[25];
    float* out = (float*)d_out;

    const int NPn = in_sizes[0];
    const int EPn = in_sizes[2] / 2;
    const int NMn = in_sizes[4];
    const int EMn = in_sizes[6] / 2;
    const int Bn  = in_sizes[8];
    const int NMAX = NPn > NMn ? NPn : NMn;
    const int EMAX = EPn > EMn ? EPn : EMn;

    char* ws = (char*)d_ws;
    size_t off = 0;
    auto alloc = [&](size_t nb) { off = (off + 255) & ~(size_t)255; size_t r = off; off += nb; return r; };
    int*   deg    = (int*)(ws + alloc(4ull * NMAX));
    int*   offs   = (int*)(ws + alloc(4ull * NMAX));
    int*   cursor = (int*)(ws + alloc(4ull * NMAX));
    int*   csr    = (int*)(ws + alloc(4ull * EMAX));
    float* csrw   = (float*)(ws + alloc(4ull * EMAX));
    float* dinv   = (float*)(ws + alloc(4ull * NMAX));
    float* h0     = (float*)(ws + alloc(4ull * NMAX * HID));
    float* h1     = (float*)(ws + alloc(4ull * NMAX * HID));
    float* pe     = (float*)(ws + alloc(4ull * Bn * HID));
    int*   cntb   = (int*)(ws + alloc(4ull * Bn));
    float* te     = (float*)(ws + alloc(4ull * Bn * HID));
    float* combo  = (float*)(ws + alloc(4ull * Bn * HID));
    int*   part   = (int*)(ws + alloc(4ull * 256));

    auto run_branch = [&](const int* res, const float* pos, const int* ei, int n, int e,
                          const float* W1, const float* b1, const float* W2, const float* b2) {
        hipMemsetAsync(deg, 0, 4ull * n, stream);
        hipMemsetAsync(cursor, 0, 4ull * n, stream);
        const int* src = ei;
        const int* dst = ei + e;
        int nb = (n + 255) / 256;
        k_degree<<<(e + 255) / 256, 256, 0, stream>>>(dst, deg, e);
        k_scan1<<<nb, 256, 0, stream>>>(deg, offs, part, n);
        k_scan2<<<1, 256, 0, stream>>>(part, nb);
        k_scan3<<<nb, 256, 0, stream>>>(offs, part, n);
        k_dinv<<<nb, 256, 0, stream>>>(deg, dinv, n);
        k_fill<<<(e + 255) / 256, 256, 0, stream>>>(src, dst, offs, cursor, dinv, csr, csrw, e);
        k_layer1<<<(n * HID + 255) / 256, 256, 0, stream>>>(res, pos, W1, h0, n);
        k_agg<<<n, HID, 0, stream>>>(h0, offs, deg, csr, csrw, dinv, b1, h1, n);
        k_gemm<<<(n + 63) / 64, 256, 0, stream>>>(h1, W2, h0, n);
        k_agg<<<n, HID, 0, stream>>>(h0, offs, deg, csr, csrw, dinv, b2, h1, n);
    };

    // protein branch -> pooled embedding
    run_branch(p_res, p_pos, p_ei, NPn, EPn, Wp1, bp1, Wp2, bp2);
    hipMemsetAsync(pe, 0, 4ull * Bn * HID, stream);
    hipMemsetAsync(cntb, 0, 4ull * Bn, stream);
    k_pool<<<(NPn + 511) / 512, HID, 0, stream>>>(h1, p_bat, pe, cntb, NPn);
    k_pool_div<<<Bn, HID, 0, stream>>>(pe, cntb);

    // molecule branch (reuses scratch; h1 = final x_m)
    run_branch(m_res, m_pos, m_ei, NMn, EMn, Wm1, bm1, Wm2, bm2);

    // timestep embedding + per-batch combo table
    k_temb<<<Bn, HID, 0, stream>>>(t, Wt1, bt1, Wt2, bt2, te);
    k_combo<<<Bn, HID, 0, stream>>>(pe, te, Wn1, bn1, combo);

    // fused noise-predictor head
    k_final<<<(NMn + 63) / 64, 256, 0, stream>>>(h1, Wn1, combo, m_bat, noisy, Wn2, bn2, out, NMn);
}

// Round 2
// 576.797 us; speedup vs baseline: 1.4930x; 1.4930x over previous
//
#include <hip/hip_runtime.h>
#include <hip/hip_bf16.h>

#define HID 128

__device__ __forceinline__ float4 f4fma(float a, float4 x, float4 y) {
    y.x += a * x.x; y.y += a * x.y; y.z += a * x.z; y.w += a * x.w; return y;
}

// ---------------- degree / scan / csr ----------------
__global__ void k_degree(const int* __restrict__ dst, int* __restrict__ deg, int e) {
    int i = blockIdx.x * blockDim.x + threadIdx.x;
    if (i < e) atomicAdd(&deg[dst[i]], 1);
}

__global__ void k_scan1(const int* __restrict__ deg, int* __restrict__ offs,
                        int* __restrict__ part, int n) {
    __shared__ int s[256];
    int tid = threadIdx.x;
    int i = blockIdx.x * 256 + tid;
    int v = (i < n) ? deg[i] : 0;
    s[tid] = v; __syncthreads();
    for (int off = 1; off < 256; off <<= 1) {
        int t = (tid >= off) ? s[tid - off] : 0;
        __syncthreads();
        s[tid] += t;
        __syncthreads();
    }
    if (i < n) offs[i] = s[tid] - v;
    if (tid == 255) part[blockIdx.x] = s[255];
}

__global__ void k_scan2(int* __restrict__ part, int nb) {
    __shared__ int s[256];
    int tid = threadIdx.x;
    int v = (tid < nb) ? part[tid] : 0;
    s[tid] = v; __syncthreads();
    for (int off = 1; off < 256; off <<= 1) {
        int t = (tid >= off) ? s[tid - off] : 0;
        __syncthreads();
        s[tid] += t;
        __syncthreads();
    }
    part[tid] = s[tid] - v;
}

// scan3 + dinv fused
__global__ void k_scan3d(int* __restrict__ offs, const int* __restrict__ part,
                         const int* __restrict__ deg, float* __restrict__ dinv, int n) {
    int i = blockIdx.x * 256 + threadIdx.x;
    if (i < n) {
        offs[i] += part[blockIdx.x];
        dinv[i] = rsqrtf((float)(deg[i] + 1)); // +1 self loop, always > 0
    }
}

__global__ void k_fill(const int* __restrict__ src, const int* __restrict__ dst,
                       const int* __restrict__ offs, int* __restrict__ cursor,
                       const float* __restrict__ dinv, int2* __restrict__ csre, int e) {
    int i = blockIdx.x * blockDim.x + threadIdx.x;
    if (i < e) {
        int s = src[i], d = dst[i];
        int p = offs[d] + atomicAdd(&cursor[d], 1);
        csre[p] = make_int2(s, __float_as_int(dinv[s]));
    }
}

// ---------------- layer 1: fused one-hot "GEMM" + pull aggregation ----------------
// msg(s) = W1[res[s]] + pos[s] . W1[20:23], computed on the fly (W1 is L1-resident)
__global__ __launch_bounds__(256) void k_agg_l1(
        const int* __restrict__ res, const float* __restrict__ pos,
        const int* __restrict__ offs, const int* __restrict__ cnt,
        const int2* __restrict__ csre, const float* __restrict__ dinv,
        const float* __restrict__ W1, const float* __restrict__ b1,
        float* __restrict__ out, int n) {
    int g = blockIdx.x * 8 + (threadIdx.x >> 5); // node per 32-lane group
    if (g >= n) return;
    int lane = threadIdx.x & 31;                 // 4 channels per lane
    const float4* W4 = (const float4*)W1;        // [23][32] of float4
    float4 w20 = W4[20 * 32 + lane], w21 = W4[21 * 32 + lane], w22 = W4[22 * 32 + lane];
    float di = dinv[g];
    // self-loop term (norm di*di; outer di applied at end)
    int rs = res[g];
    float px = pos[g * 3 + 0], py = pos[g * 3 + 1], pz = pos[g * 3 + 2];
    float4 u = W4[rs * 32 + lane];
    u = f4fma(px, w20, u); u = f4fma(py, w21, u); u = f4fma(pz, w22, u);
    float4 acc = make_float4(di * u.x, di * u.y, di * u.z, di * u.w);
    int s0 = offs[g], m = cnt[g];
    for (int e = 0; e < m; ++e) {
        int2 ed = csre[s0 + e];
        int s = ed.x; float w = __int_as_float(ed.y);
        int r2 = res[s];
        float qx = pos[s * 3 + 0], qy = pos[s * 3 + 1], qz = pos[s * 3 + 2];
        float4 v = W4[r2 * 32 + lane];
        v = f4fma(qx, w20, v); v = f4fma(qy, w21, v); v = f4fma(qz, w22, v);
        acc = f4fma(w, v, acc);
    }
    float4 b = ((const float4*)b1)[lane];
    float4 o;
    o.x = fmaxf(di * acc.x + b.x, 0.f);
    o.y = fmaxf(di * acc.y + b.y, 0.f);
    o.z = fmaxf(di * acc.z + b.z, 0.f);
    o.w = fmaxf(di * acc.w + b.w, 0.f);
    ((float4*)out)[(size_t)g * 32 + lane] = o;
}

// ---------------- layer 2 pull aggregation (dense gather, float4 lanes) ----------------
__global__ __launch_bounds__(256) void k_agg2(
        const float4* __restrict__ h, const int* __restrict__ offs,
        const int* __restrict__ cnt, const int2* __restrict__ csre,
        const float* __restrict__ dinv, const float* __restrict__ bias,
        float4* __restrict__ out, int n) {
    int g = blockIdx.x * 8 + (threadIdx.x >> 5);
    if (g >= n) return;
    int lane = threadIdx.x & 31;
    float di = dinv[g];
    float4 hv = h[(size_t)g * 32 + lane];
    float4 acc = make_float4(di * hv.x, di * hv.y, di * hv.z, di * hv.w);
    int s0 = offs[g], m = cnt[g];
    for (int e = 0; e < m; ++e) {
        int2 ed = csre[s0 + e];
        float w = __int_as_float(ed.y);
        float4 v = h[(size_t)ed.x * 32 + lane];
        acc = f4fma(w, v, acc);
    }
    float4 b = ((const float4*)bias)[lane];
    float4 o;
    o.x = fmaxf(di * acc.x + b.x, 0.f);
    o.y = fmaxf(di * acc.y + b.y, 0.f);
    o.z = fmaxf(di * acc.z + b.z, 0.f);
    o.w = fmaxf(di * acc.w + b.w, 0.f);
    out[(size_t)g * 32 + lane] = o;
}

// ---------------- fp32 tiled GEMM: C[n,128] = A[n,128] @ W[128,128] ----------------
__global__ __launch_bounds__(256) void k_gemm(const float* __restrict__ A,
                                              const float* __restrict__ W,
                                              float* __restrict__ C, int n) {
    __shared__ float As[32][68];
    __shared__ float Ws[32][132];
    const int tid = threadIdx.x;
    const int tx = tid & 15;
    const int ty = tid >> 4;
    const int r0 = blockIdx.x * 64;
    float acc[4][8] = {};
    for (int kk = 0; kk < HID; kk += 32) {
        {
            int kq = tid & 7, row = tid >> 3;
            #pragma unroll
            for (int hh = 0; hh < 2; ++hh, row += 32) {
                int gr = r0 + row;
                float4 a = (gr < n) ? *(const float4*)&A[(size_t)gr * HID + kk + kq * 4]
                                    : make_float4(0.f, 0.f, 0.f, 0.f);
                As[kq * 4 + 0][row] = a.x; As[kq * 4 + 1][row] = a.y;
                As[kq * 4 + 2][row] = a.z; As[kq * 4 + 3][row] = a.w;
            }
        }
        {
            int cq = tid & 31, kr = tid >> 5;
            #pragma unroll
            for (int hh = 0; hh < 4; ++hh, kr += 8)
                *(float4*)&Ws[kr][cq * 4] = *(const float4*)&W[(size_t)(kk + kr) * HID + cq * 4];
        }
        __syncthreads();
        #pragma unroll
        for (int k = 0; k < 32; ++k) {
            float4 a  = *(const float4*)&As[k][ty * 4];
            float4 w0 = *(const float4*)&Ws[k][tx * 8];
            float4 w1 = *(const float4*)&Ws[k][tx * 8 + 4];
            float av[4] = {a.x, a.y, a.z, a.w};
            float wv[8] = {w0.x, w0.y, w0.z, w0.w, w1.x, w1.y, w1.z, w1.w};
            #pragma unroll
            for (int r = 0; r < 4; ++r)
                #pragma unroll
                for (int c = 0; c < 8; ++c) acc[r][c] += av[r] * wv[c];
        }
        __syncthreads();
    }
    #pragma unroll
    for (int r = 0; r < 4; ++r) {
        int gr = r0 + ty * 4 + r;
        if (gr < n) {
            *(float4*)&C[(size_t)gr * HID + tx * 8]     = make_float4(acc[r][0], acc[r][1], acc[r][2], acc[r][3]);
            *(float4*)&C[(size_t)gr * HID + tx * 8 + 4] = make_float4(acc[r][4], acc[r][5], acc[r][6], acc[r][7]);
        }
    }
}

// ---------------- mean pool: 64 rows/block, run-length + atomics ----------------
__global__ void k_pool(const float* __restrict__ x, const int* __restrict__ batch,
                       float* __restrict__ pool, int* __restrict__ cnt, int n) {
    const int ROWS = 64;
    int start = blockIdx.x * ROWS;
    if (start >= n) return;
    int end = start + ROWS; if (end > n) end = n;
    int c = threadIdx.x;
    float acc = 0.f;
    int cur = batch[start];
    int run = 0;
    for (int r = start; r < end; ++r) {
        int b = batch[r];
        if (b != cur) {
            atomicAdd(&pool[cur * HID + c], acc);
            if (c == 0) atomicAdd(&cnt[cur], run);
            acc = 0.f; run = 0; cur = b;
        }
        acc += x[(size_t)r * HID + c];
        run++;
    }
    atomicAdd(&pool[cur * HID + c], acc);
    if (c == 0) atomicAdd(&cnt[cur], run);
}

// ---------------- pool-div + timestep emb + combo table, fused ----------------
// combo[b] = (pool[b]/cnt[b]) @ Wn1[128:256] + te[b] @ Wn1[256:384] + bn1
__global__ void k_combo2(const int* __restrict__ t, const float* __restrict__ Wt1,
                         const float* __restrict__ bt1, const float* __restrict__ Wt2,
                         const float* __restrict__ bt2,
                         const float* __restrict__ pool, const int* __restrict__ cntb,
                         const float* __restrict__ Wn1, const float* __restrict__ bn1,
                         float* __restrict__ combo) {
    __shared__ float th[HID];  // relu(t*Wt1+bt1)
    __shared__ float pe[HID];
    __shared__ float te[HID];
    int b = blockIdx.x, c = threadIdx.x;
    float tv = (float)t[b];
    float hv = tv * Wt1[c] + bt1[c];
    th[c] = hv > 0.f ? hv : 0.f;
    float dcnt = (float)cntb[b]; if (dcnt < 1.f) dcnt = 1.f;
    pe[c] = pool[b * HID + c] / dcnt;
    __syncthreads();
    float s = bt2[c];
    for (int k = 0; k < HID; ++k) s += th[k] * Wt2[k * HID + c];
    te[c] = s;
    __syncthreads();
    const float* Wp = Wn1 + 128 * HID;
    const float* Wt = Wn1 + 256 * HID;
    float o = bn1[c];
    for (int k = 0; k < HID; ++k)
        o += pe[k] * Wp[k * HID + c] + te[k] * Wt[k * HID + c];
    combo[b * HID + c] = o;
}

// ---------------- fused final head ----------------
__global__ __launch_bounds__(256) void k_final(const float* __restrict__ A /*x_m*/,
        const float* __restrict__ Wn1, const float* __restrict__ combo,
        const int* __restrict__ mbatch, const float* __restrict__ noisy,
        const float* __restrict__ Wn2, const float* __restrict__ bn2,
        float* __restrict__ out, int n) {
    __shared__ float As[32][68];
    __shared__ float Ws[32][132];
    __shared__ float hsm[64][133];
    const int tid = threadIdx.x;
    const int tx = tid & 15;
    const int ty = tid >> 4;
    const int r0 = blockIdx.x * 64;
    float acc[4][8] = {};
    for (int kk = 0; kk < HID; kk += 32) {
        {
            int kq = tid & 7, row = tid >> 3;
            #pragma unroll
            for (int hh = 0; hh < 2; ++hh, row += 32) {
                int gr = r0 + row;
                float4 a = (gr < n) ? *(const float4*)&A[(size_t)gr * HID + kk + kq * 4]
                                    : make_float4(0.f, 0.f, 0.f, 0.f);
                As[kq * 4 + 0][row] = a.x; As[kq * 4 + 1][row] = a.y;
                As[kq * 4 + 2][row] = a.z; As[kq * 4 + 3][row] = a.w;
            }
        }
        {
            int cq = tid & 31, kr = tid >> 5;
            #pragma unroll
            for (int hh = 0; hh < 4; ++hh, kr += 8)
                *(float4*)&Ws[kr][cq * 4] = *(const float4*)&Wn1[(size_t)(kk + kr) * HID + cq * 4];
        }
        __syncthreads();
        #pragma unroll
        for (int k = 0; k < 32; ++k) {
            float4 a  = *(const float4*)&As[k][ty * 4];
            float4 w0 = *(const float4*)&Ws[k][tx * 8];
            float4 w1 = *(const float4*)&Ws[k][tx * 8 + 4];
            float av[4] = {a.x, a.y, a.z, a.w};
            float wv[8] = {w0.x, w0.y, w0.z, w0.w, w1.x, w1.y, w1.z, w1.w};
            #pragma unroll
            for (int r = 0; r < 4; ++r)
                #pragma unroll
                for (int c = 0; c < 8; ++c) acc[r][c] += av[r] * wv[c];
        }
        __syncthreads();
    }
    const float* Wna = Wn1 + 384 * HID;
    #pragma unroll
    for (int r = 0; r < 4; ++r) {
        int lr = ty * 4 + r;
        int gr = r0 + lr;
        if (gr < n) {
            int b = mbatch[gr];
            float na0 = noisy[gr * 3 + 0], na1 = noisy[gr * 3 + 1], na2 = noisy[gr * 3 + 2];
            #pragma unroll
            for (int c = 0; c < 8; ++c) {
                int col = tx * 8 + c;
                float v = acc[r][c]
                        + na0 * Wna[col] + na1 * Wna[HID + col] + na2 * Wna[2 * HID + col]
                        + combo[b * HID + col];
                hsm[lr][col] = v > 0.f ? v : 0.f;
            }
        }
    }
    __syncthreads();
    if (tid < 192) {
        int lr = tid / 3, j = tid - lr * 3;
        int gr = r0 + lr;
        if (gr < n) {
            float s = bn2[j];
            for (int c = 0; c < HID; ++c) s += hsm[lr][c] * Wn2[c * 3 + j];
            out[(size_t)gr * 3 + j] = s;
        }
    }
}

// ---------------- host ----------------
extern "C" void kernel_launch(void* const* d_in, const int* in_sizes, int n_in,
                              void* d_out, int out_size, void* d_ws, size_t ws_size,
                              hipStream_t stream) {
    const int*   p_res  = (const int*)d_in[0];
    const float* p_pos  = (const float*)d_in[1];
    const int*   p_ei   = (const int*)d_in[2];
    const int*   p_bat  = (const int*)d_in[3];
    const int*   m_res  = (const int*)d_in[4];
    const float* m_pos  = (const float*)d_in[5];
    const int*   m_ei   = (const int*)d_in[6];
    const int*   m_bat  = (const int*)d_in[7];
    const int*   t      = (const int*)d_in[8];
    const float* noisy  = (const float*)d_in[9];
    const float* Wp1 = (const float*)d_in[10], *bp1 = (const float*)d_in[11];
    const float* Wp2 = (const float*)d_in[12], *bp2 = (const float*)d_in[13];
    const float* Wm1 = (const float*)d_in[14], *bm1 = (const float*)d_in[15];
    const float* Wm2 = (const float*)d_in[16], *bm2 = (const float*)d_in[17];
    const float* Wt1 = (const float*)d_in[18], *bt1 = (const float*)d_in[19];
    const float* Wt2 = (const float*)d_in[20], *bt2 = (const float*)d_in[21];
    const float* Wn1 = (const float*)d_in[22], *bn1 = (const float*)d_in[23];
    const float* Wn2 = (const float*)d_in[24], *bn2 = (const float*)d_in[25];
    float* out = (float*)d_out;

    const int NPn = in_sizes[0];
    const int EPn = in_sizes[2] / 2;
    const int NMn = in_sizes[4];
    const int EMn = in_sizes[6] / 2;
    const int Bn  = in_sizes[8];
    const int NMAX = NPn > NMn ? NPn : NMn;
    const int EMAX = EPn > EMn ? EPn : EMn;

    char* ws = (char*)d_ws;
    size_t off = 0;
    auto alloc = [&](size_t nb) { off = (off + 255) & ~(size_t)255; size_t r = off; off += nb; return r; };
    int*   deg    = (int*)(ws + alloc(4ull * NMAX));
    int*   offs   = (int*)(ws + alloc(4ull * NMAX));
    int*   cursor = (int*)(ws + alloc(4ull * NMAX));
    int2*  csre   = (int2*)(ws + alloc(8ull * EMAX));
    float* dinv   = (float*)(ws + alloc(4ull * NMAX));
    float* h0     = (float*)(ws + alloc(4ull * NMAX * HID));
    float* h1     = (float*)(ws + alloc(4ull * NMAX * HID));
    float* pool   = (float*)(ws + alloc(4ull * Bn * HID));
    int*   cntb   = (int*)(ws + alloc(4ull * Bn));
    float* combo  = (float*)(ws + alloc(4ull * Bn * HID));
    int*   part   = (int*)(ws + alloc(4ull * 256));

    auto run_branch = [&](const int* res, const float* pos, const int* ei, int n, int e,
                          const float* W1, const float* b1, const float* W2, const float* b2) {
        hipMemsetAsync(deg, 0, 4ull * n, stream);
        hipMemsetAsync(cursor, 0, 4ull * n, stream);
        const int* src = ei;
        const int* dst = ei + e;
        int nb = (n + 255) / 256;
        k_degree<<<(e + 255) / 256, 256, 0, stream>>>(dst, deg, e);
        k_scan1<<<nb, 256, 0, stream>>>(deg, offs, part, n);
        k_scan2<<<1, 256, 0, stream>>>(part, nb);
        k_scan3d<<<nb, 256, 0, stream>>>(offs, part, deg, dinv, n);
        k_fill<<<(e + 255) / 256, 256, 0, stream>>>(src, dst, offs, cursor, dinv, csre, e);
        k_agg_l1<<<(n + 7) / 8, 256, 0, stream>>>(res, pos, offs, deg, csre, dinv, W1, b1, h1, n);
        k_gemm<<<(n + 63) / 64, 256, 0, stream>>>(h1, W2, h0, n);
        k_agg2<<<(n + 7) / 8, 256, 0, stream>>>((const float4*)h0, offs, deg, csre, dinv, b2,
                                                (float4*)h1, n);
    };

    // protein branch -> pooled embedding
    run_branch(p_res, p_pos, p_ei, NPn, EPn, Wp1, bp1, Wp2, bp2);
    hipMemsetAsync(pool, 0, 4ull * Bn * HID, stream);
    hipMemsetAsync(cntb, 0, 4ull * Bn, stream);
    k_pool<<<(NPn + 63) / 64, HID, 0, stream>>>(h1, p_bat, pool, cntb, NPn);
    k_combo2<<<Bn, HID, 0, stream>>>(t, Wt1, bt1, Wt2, bt2, pool, cntb, Wn1, bn1, combo);

    // molecule branch (reuses scratch; h1 = final x_m)
    run_branch(m_res, m_pos, m_ei, NMn, EMn, Wm1, bm1, Wm2, bm2);

    // fused noise-predictor head
    k_final<<<(NMn + 63) / 64, 256, 0, stream>>>(h1, Wn1, combo, m_bat, noisy, Wn2, bn2, out, NMn);
}

// Round 3
// 461.178 us; speedup vs baseline: 1.8673x; 1.2507x over previous
//
#include <hip/hip_runtime.h>
#include <hip/hip_bf16.h>

#define HID 128

__device__ __forceinline__ float4 f4fma(float a, float4 x, float4 y) {
    y.x += a * x.x; y.y += a * x.y; y.z += a * x.z; y.w += a * x.w; return y;
}
__device__ __forceinline__ unsigned f2bf2(float lo, float hi) {
    unsigned ul = __float_as_uint(lo), uh = __float_as_uint(hi);
    ul = (ul + 0x7FFF + ((ul >> 16) & 1)) >> 16;
    uh = (uh + 0x7FFF + ((uh >> 16) & 1)) & 0xFFFF0000u;
    return ul | uh;
}
__device__ __forceinline__ float bf2f(unsigned short b) {
    return __uint_as_float(((unsigned)b) << 16);
}

// ---------------- degree over two edge segments ----------------
__global__ void k_degree(const int* __restrict__ d1, int e1,
                         const int* __restrict__ d2, int e2, int base2,
                         int* __restrict__ deg) {
    int i = blockIdx.x * blockDim.x + threadIdx.x;
    if (i < e1) atomicAdd(&deg[d1[i]], 1);
    else if (i < e1 + e2) atomicAdd(&deg[d2[i - e1] + base2], 1);
}

__global__ void k_scan1(const int* __restrict__ deg, int* __restrict__ offs,
                        int* __restrict__ part, int n) {
    __shared__ int s[256];
    int tid = threadIdx.x;
    int i = blockIdx.x * 256 + tid;
    int v = (i < n) ? deg[i] : 0;
    s[tid] = v; __syncthreads();
    for (int off = 1; off < 256; off <<= 1) {
        int t = (tid >= off) ? s[tid - off] : 0;
        __syncthreads();
        s[tid] += t;
        __syncthreads();
    }
    if (i < n) offs[i] = s[tid] - v;
    if (tid == 255) part[blockIdx.x] = s[255];
}

__global__ void k_scan2(int* __restrict__ part, int nb) {
    __shared__ int s[512];
    int tid = threadIdx.x;
    int v = (tid < nb) ? part[tid] : 0;
    s[tid] = v; __syncthreads();
    for (int off = 1; off < 512; off <<= 1) {
        int t = (tid >= off) ? s[tid - off] : 0;
        __syncthreads();
        s[tid] += t;
        __syncthreads();
    }
    part[tid] = s[tid] - v;
}

// scan3 + dinv + offs copy (atomic cursor base), fused
__global__ void k_scan3d(int* __restrict__ offs, int* __restrict__ ofs2,
                         const int* __restrict__ part,
                         const int* __restrict__ deg, float* __restrict__ dinv, int n) {
    int i = blockIdx.x * 256 + threadIdx.x;
    if (i < n) {
        int o = offs[i] + part[blockIdx.x];
        offs[i] = o;
        ofs2[i] = o;
        dinv[i] = rsqrtf((float)(deg[i] + 1)); // +1 self loop, always > 0
    }
}

__global__ void k_fill(const int* __restrict__ s1, const int* __restrict__ d1, int e1,
                       const int* __restrict__ s2, const int* __restrict__ d2, int e2, int base2,
                       int* __restrict__ ofs2, const float* __restrict__ dinv,
                       int2* __restrict__ csre) {
    int i = blockIdx.x * blockDim.x + threadIdx.x;
    int s, d;
    if (i < e1) { s = s1[i]; d = d1[i]; }
    else if (i < e1 + e2) { s = s2[i - e1] + base2; d = d2[i - e1] + base2; }
    else return;
    int p = atomicAdd(&ofs2[d], 1);
    csre[p] = make_int2(s, __float_as_int(dinv[s]));
}

// ---------------- layer 1: fused one-hot "GEMM" + pull aggregation ----------------
__global__ __launch_bounds__(256) void k_agg_l1(
        const int* __restrict__ res1, const float* __restrict__ pos1,
        const int* __restrict__ res2, const float* __restrict__ pos2,
        int np, int np64, int nm,
        const int* __restrict__ offs, const int* __restrict__ cnt,
        const int2* __restrict__ csre, const float* __restrict__ dinv,
        const float* __restrict__ W1a, const float* __restrict__ b1a,
        const float* __restrict__ W1b, const float* __restrict__ b1b,
        float* __restrict__ out) {
    int g = blockIdx.x * 8 + (threadIdx.x >> 5);
    int lane = threadIdx.x & 31;
    const int* res; const float* pos; const float4* W4; const float4* bb; int base;
    if (g < np) { res = res1; pos = pos1; W4 = (const float4*)W1a; bb = (const float4*)b1a; base = 0; }
    else if (g < np64) return;
    else if (g < np64 + nm) { res = res2; pos = pos2; W4 = (const float4*)W1b; bb = (const float4*)b1b; base = np64; }
    else return;
    int lg = g - base;
    float4 w20 = W4[20 * 32 + lane], w21 = W4[21 * 32 + lane], w22 = W4[22 * 32 + lane];
    float di = dinv[g];
    float4 u = W4[res[lg] * 32 + lane];
    u = f4fma(pos[lg * 3 + 0], w20, u);
    u = f4fma(pos[lg * 3 + 1], w21, u);
    u = f4fma(pos[lg * 3 + 2], w22, u);
    float4 acc = make_float4(di * u.x, di * u.y, di * u.z, di * u.w);
    int s0 = offs[g], m = cnt[g];
    int e = 0;
    for (; e + 1 < m; e += 2) {
        int2 e0 = csre[s0 + e], e1 = csre[s0 + e + 1];
        int a0 = e0.x - base, a1 = e1.x - base;
        int r0 = res[a0], r1 = res[a1];
        float qx0 = pos[a0 * 3 + 0], qy0 = pos[a0 * 3 + 1], qz0 = pos[a0 * 3 + 2];
        float qx1 = pos[a1 * 3 + 0], qy1 = pos[a1 * 3 + 1], qz1 = pos[a1 * 3 + 2];
        float4 v0 = W4[r0 * 32 + lane];
        float4 v1 = W4[r1 * 32 + lane];
        v0 = f4fma(qx0, w20, v0); v0 = f4fma(qy0, w21, v0); v0 = f4fma(qz0, w22, v0);
        v1 = f4fma(qx1, w20, v1); v1 = f4fma(qy1, w21, v1); v1 = f4fma(qz1, w22, v1);
        acc = f4fma(__int_as_float(e0.y), v0, acc);
        acc = f4fma(__int_as_float(e1.y), v1, acc);
    }
    if (e < m) {
        int2 e0 = csre[s0 + e];
        int a0 = e0.x - base;
        float4 v0 = W4[res[a0] * 32 + lane];
        v0 = f4fma(pos[a0 * 3 + 0], w20, v0);
        v0 = f4fma(pos[a0 * 3 + 1], w21, v0);
        v0 = f4fma(pos[a0 * 3 + 2], w22, v0);
        acc = f4fma(__int_as_float(e0.y), v0, acc);
    }
    float4 b = bb[lane];
    float4 o;
    o.x = fmaxf(di * acc.x + b.x, 0.f);
    o.y = fmaxf(di * acc.y + b.y, 0.f);
    o.z = fmaxf(di * acc.z + b.z, 0.f);
    o.w = fmaxf(di * acc.w + b.w, 0.f);
    ((float4*)out)[(size_t)g * 32 + lane] = o;
}

// ---------------- layer 2 pull aggregation: bf16 gather, fp32 out ----------------
__global__ __launch_bounds__(256) void k_agg2(
        const ushort4* __restrict__ hb, const int* __restrict__ offs,
        const int* __restrict__ cnt, const int2* __restrict__ csre,
        const float* __restrict__ dinv,
        int np, int np64, int nm,
        const float* __restrict__ b2a, const float* __restrict__ b2b,
        float4* __restrict__ out) {
    int g = blockIdx.x * 8 + (threadIdx.x >> 5);
    const float4* bb;
    if (g < np) bb = (const float4*)b2a;
    else if (g < np64) return;
    else if (g < np64 + nm) bb = (const float4*)b2b;
    else return;
    int lane = threadIdx.x & 31;
    float di = dinv[g];
    ushort4 hs = hb[(size_t)g * 32 + lane];
    float4 acc = make_float4(di * bf2f(hs.x), di * bf2f(hs.y), di * bf2f(hs.z), di * bf2f(hs.w));
    int s0 = offs[g], m = cnt[g];
    int e = 0;
    for (; e + 1 < m; e += 2) {
        int2 e0 = csre[s0 + e], e1 = csre[s0 + e + 1];
        ushort4 u0 = hb[(size_t)e0.x * 32 + lane];
        ushort4 u1 = hb[(size_t)e1.x * 32 + lane];
        float4 v0 = make_float4(bf2f(u0.x), bf2f(u0.y), bf2f(u0.z), bf2f(u0.w));
        float4 v1 = make_float4(bf2f(u1.x), bf2f(u1.y), bf2f(u1.z), bf2f(u1.w));
        acc = f4fma(__int_as_float(e0.y), v0, acc);
        acc = f4fma(__int_as_float(e1.y), v1, acc);
    }
    if (e < m) {
        int2 e0 = csre[s0 + e];
        ushort4 u0 = hb[(size_t)e0.x * 32 + lane];
        float4 v0 = make_float4(bf2f(u0.x), bf2f(u0.y), bf2f(u0.z), bf2f(u0.w));
        acc = f4fma(__int_as_float(e0.y), v0, acc);
    }
    float4 b = bb[lane];
    float4 o;
    o.x = fmaxf(di * acc.x + b.x, 0.f);
    o.y = fmaxf(di * acc.y + b.y, 0.f);
    o.z = fmaxf(di * acc.z + b.z, 0.f);
    o.w = fmaxf(di * acc.w + b.w, 0.f);
    out[(size_t)g * 32 + lane] = o;
}

// ---------------- fp32 tiled GEMM: Cb[r,128](bf16) = A[r,128] @ W[128,128] ----------------
__global__ __launch_bounds__(256) void k_gemm(const float* __restrict__ A,
                                              const float* __restrict__ W2a,
                                              const float* __restrict__ W2b,
                                              int nb1, int np64, int ntot,
                                              unsigned* __restrict__ Cb) {
    __shared__ float As[32][68];
    __shared__ float Ws[32][132];
    const int tid = threadIdx.x;
    const int tx = tid & 15;
    const int ty = tid >> 4;
    const float* W; int r0;
    if ((int)blockIdx.x < nb1) { W = W2a; r0 = blockIdx.x * 64; }
    else { W = W2b; r0 = np64 + (blockIdx.x - nb1) * 64; }
    float acc[4][8] = {};
    for (int kk = 0; kk < HID; kk += 32) {
        {
            int kq = tid & 7, row = tid >> 3;
            #pragma unroll
            for (int hh = 0; hh < 2; ++hh, row += 32) {
                int gr = r0 + row;
                float4 a = (gr < ntot) ? *(const float4*)&A[(size_t)gr * HID + kk + kq * 4]
                                       : make_float4(0.f, 0.f, 0.f, 0.f);
                As[kq * 4 + 0][row] = a.x; As[kq * 4 + 1][row] = a.y;
                As[kq * 4 + 2][row] = a.z; As[kq * 4 + 3][row] = a.w;
            }
        }
        {
            int cq = tid & 31, kr = tid >> 5;
            #pragma unroll
            for (int hh = 0; hh < 4; ++hh, kr += 8)
                *(float4*)&Ws[kr][cq * 4] = *(const float4*)&W[(size_t)(kk + kr) * HID + cq * 4];
        }
        __syncthreads();
        #pragma unroll
        for (int k = 0; k < 32; ++k) {
            float4 a  = *(const float4*)&As[k][ty * 4];
            float4 w0 = *(const float4*)&Ws[k][tx * 8];
            float4 w1 = *(const float4*)&Ws[k][tx * 8 + 4];
            float av[4] = {a.x, a.y, a.z, a.w};
            float wv[8] = {w0.x, w0.y, w0.z, w0.w, w1.x, w1.y, w1.z, w1.w};
            #pragma unroll
            for (int r = 0; r < 4; ++r)
                #pragma unroll
                for (int c = 0; c < 8; ++c) acc[r][c] += av[r] * wv[c];
        }
        __syncthreads();
    }
    #pragma unroll
    for (int r = 0; r < 4; ++r) {
        int gr = r0 + ty * 4 + r;
        if (gr < ntot) {
            uint4 pk;
            pk.x = f2bf2(acc[r][0], acc[r][1]);
            pk.y = f2bf2(acc[r][2], acc[r][3]);
            pk.z = f2bf2(acc[r][4], acc[r][5]);
            pk.w = f2bf2(acc[r][6], acc[r][7]);
            *(uint4*)&Cb[(size_t)gr * 64 + tx * 4] = pk; // 64 uints per row
        }
    }
}

// ---------------- mean pool: 64 rows/block ----------------
__global__ void k_pool(const float* __restrict__ x, const int* __restrict__ batch,
                       float* __restrict__ pool, int* __restrict__ cnt, int n) {
    const int ROWS = 64;
    int start = blockIdx.x * ROWS;
    if (start >= n) return;
    int end = start + ROWS; if (end > n) end = n;
    int c = threadIdx.x;
    float acc = 0.f;
    int cur = batch[start];
    int run = 0;
    for (int r = start; r < end; ++r) {
        int b = batch[r];
        if (b != cur) {
            atomicAdd(&pool[cur * HID + c], acc);
            if (c == 0) atomicAdd(&cnt[cur], run);
            acc = 0.f; run = 0; cur = b;
        }
        acc += x[(size_t)r * HID + c];
        run++;
    }
    atomicAdd(&pool[cur * HID + c], acc);
    if (c == 0) atomicAdd(&cnt[cur], run);
}

// ---------------- pool-div + timestep emb + combo table ----------------
__global__ void k_combo2(const int* __restrict__ t, const float* __restrict__ Wt1,
                         const float* __restrict__ bt1, const float* __restrict__ Wt2,
                         const float* __restrict__ bt2,
                         const float* __restrict__ pool, const int* __restrict__ cntb,
                         const float* __restrict__ Wn1, const float* __restrict__ bn1,
                         float* __restrict__ combo) {
    __shared__ float th[HID];
    __shared__ float pe[HID];
    __shared__ float te[HID];
    int b = blockIdx.x, c = threadIdx.x;
    float tv = (float)t[b];
    float hv = tv * Wt1[c] + bt1[c];
    th[c] = hv > 0.f ? hv : 0.f;
    float dcnt = (float)cntb[b]; if (dcnt < 1.f) dcnt = 1.f;
    pe[c] = pool[b * HID + c] / dcnt;
    __syncthreads();
    float s = bt2[c];
    for (int k = 0; k < HID; ++k) s += th[k] * Wt2[k * HID + c];
    te[c] = s;
    __syncthreads();
    const float* Wp = Wn1 + 128 * HID;
    const float* Wt = Wn1 + 256 * HID;
    float o = bn1[c];
    for (int k = 0; k < HID; ++k)
        o += pe[k] * Wp[k * HID + c] + te[k] * Wt[k * HID + c];
    combo[b * HID + c] = o;
}

// ---------------- fused final head ----------------
__global__ __launch_bounds__(256) void k_final(const float* __restrict__ A,
        const float* __restrict__ Wn1, const float* __restrict__ combo,
        const int* __restrict__ mbatch, const float* __restrict__ noisy,
        const float* __restrict__ Wn2, const float* __restrict__ bn2,
        float* __restrict__ out, int n) {
    __shared__ float As[32][68];
    __shared__ float Ws[32][132];
    __shared__ float hsm[64][133];
    const int tid = threadIdx.x;
    const int tx = tid & 15;
    const int ty = tid >> 4;
    const int r0 = blockIdx.x * 64;
    float acc[4][8] = {};
    for (int kk = 0; kk < HID; kk += 32) {
        {
            int kq = tid & 7, row = tid >> 3;
            #pragma unroll
            for (int hh = 0; hh < 2; ++hh, row += 32) {
                int gr = r0 + row;
                float4 a = (gr < n) ? *(const float4*)&A[(size_t)gr * HID + kk + kq * 4]
                                    : make_float4(0.f, 0.f, 0.f, 0.f);
                As[kq * 4 + 0][row] = a.x; As[kq * 4 + 1][row] = a.y;
                As[kq * 4 + 2][row] = a.z; As[kq * 4 + 3][row] = a.w;
            }
        }
        {
            int cq = tid & 31, kr = tid >> 5;
            #pragma unroll
            for (int hh = 0; hh < 4; ++hh, kr += 8)
                *(float4*)&Ws[kr][cq * 4] = *(const float4*)&Wn1[(size_t)(kk + kr) * HID + cq * 4];
        }
        __syncthreads();
        #pragma unroll
        for (int k = 0; k < 32; ++k) {
            float4 a  = *(const float4*)&As[k][ty * 4];
            float4 w0 = *(const float4*)&Ws[k][tx * 8];
            float4 w1 = *(const float4*)&Ws[k][tx * 8 + 4];
            float av[4] = {a.x, a.y, a.z, a.w};
            float wv[8] = {w0.x, w0.y, w0.z, w0.w, w1.x, w1.y, w1.z, w1.w};
            #pragma unroll
            for (int r = 0; r < 4; ++r)
                #pragma unroll
                for (int c = 0; c < 8; ++c) acc[r][c] += av[r] * wv[c];
        }
        __syncthreads();
    }
    const float* Wna = Wn1 + 384 * HID;
    #pragma unroll
    for (int r = 0; r < 4; ++r) {
        int lr = ty * 4 + r;
        int gr = r0 + lr;
        if (gr < n) {
            int b = mbatch[gr];
            float na0 = noisy[gr * 3 + 0], na1 = noisy[gr * 3 + 1], na2 = noisy[gr * 3 + 2];
            #pragma unroll
            for (int c = 0; c < 8; ++c) {
                int col = tx * 8 + c;
                float v = acc[r][c]
                        + na0 * Wna[col] + na1 * Wna[HID + col] + na2 * Wna[2 * HID + col]
                        + combo[b * HID + col];
                hsm[lr][col] = v > 0.f ? v : 0.f;
            }
        }
    }
    __syncthreads();
    if (tid < 192) {
        int lr = tid / 3, j = tid - lr * 3;
        int gr = r0 + lr;
        if (gr < n) {
            float s = bn2[j];
            for (int c = 0; c < HID; ++c) s += hsm[lr][c] * Wn2[c * 3 + j];
            out[(size_t)gr * 3 + j] = s;
        }
    }
}

// ---------------- host ----------------
extern "C" void kernel_launch(void* const* d_in, const int* in_sizes, int n_in,
                              void* d_out, int out_size, void* d_ws, size_t ws_size,
                              hipStream_t stream) {
    const int*   p_res  = (const int*)d_in[0];
    const float* p_pos  = (const float*)d_in[1];
    const int*   p_ei   = (const int*)d_in[2];
    const int*   p_bat  = (const int*)d_in[3];
    const int*   m_res  = (const int*)d_in[4];
    const float* m_pos  = (const float*)d_in[5];
    const int*   m_ei   = (const int*)d_in[6];
    const int*   m_bat  = (const int*)d_in[7];
    const int*   t      = (const int*)d_in[8];
    const float* noisy  = (const float*)d_in[9];
    const float* Wp1 = (const float*)d_in[10], *bp1 = (const float*)d_in[11];
    const float* Wp2 = (const float*)d_in[12], *bp2 = (const float*)d_in[13];
    const float* Wm1 = (const float*)d_in[14], *bm1 = (const float*)d_in[15];
    const float* Wm2 = (const float*)d_in[16], *bm2 = (const float*)d_in[17];
    const float* Wt1 = (const float*)d_in[18], *bt1 = (const float*)d_in[19];
    const float* Wt2 = (const float*)d_in[20], *bt2 = (const float*)d_in[21];
    const float* Wn1 = (const float*)d_in[22], *bn1 = (const float*)d_in[23];
    const float* Wn2 = (const float*)d_in[24], *bn2 = (const float*)d_in[25];
    float* out = (float*)d_out;

    const int NP = in_sizes[0];
    const int EP = in_sizes[2] / 2;
    const int NM = in_sizes[4];
    const int EM = in_sizes[6] / 2;
    const int B  = in_sizes[8];
    auto al64 = [](int x) { return (x + 63) & ~63; };

    // merged layout sizes
    const int np64 = al64(NP);
    const long ntot_m = (long)np64 + NM;
    const long e2sum = (long)EP + EM;

    // ws requirement for merged path
    auto align256 = [](size_t x) { return (x + 255) & ~(size_t)255; };
    size_t req = 0;
    auto count = [&](size_t nb) { req = align256(req) + nb; };
    count(4ull * ntot_m);            // deg
    count(4ull * ntot_m);            // offs
    count(4ull * ntot_m);            // ofs2
    count(4ull * ntot_m);            // dinv
    count(8ull * e2sum);             // csre
    count(4ull * ntot_m * HID);      // h1 fp32
    count(2ull * ntot_m * HID);      // hb bf16
    count(4ull * (size_t)B * (HID + 1)); // pool + cntb
    count(4ull * 512);               // part
    bool merged = ws_size >= req + 4096;

    char* ws = (char*)d_ws;
    size_t off = 0;
    auto alloc = [&](size_t nb) { off = align256(off); size_t r = off; off += nb; return r; };

    // pipeline issuing lambda (handles one or two segments)
    auto pipeline = [&](int np_, int np64_, int nm_,
                        const int* ei1, int e1, const int* ei2, int e2,
                        const int* res1, const float* pos1, const int* res2, const float* pos2,
                        const float* W1a, const float* b1a, const float* W1b, const float* b1b,
                        const float* W2a, const float* W2b, const float* b2a, const float* b2b,
                        int* deg, int* offs, int* ofs2, float* dinv, int2* csre,
                        float* h1, unsigned* hb) {
        const int ntot = np64_ + nm_;
        const long etot = (long)e1 + e2;
        const int nbs = (ntot + 255) / 256;
        const int base2 = np64_;
        const int* s1 = ei1, *d1 = ei1 + e1;
        const int* s2 = ei2, *d2 = ei2 + e2;
        hipMemsetAsync(deg, 0, 4ull * ntot, stream);
        k_degree<<<(int)((etot + 255) / 256), 256, 0, stream>>>(d1, e1, d2, e2, base2, deg);
        k_scan1<<<nbs, 256, 0, stream>>>(deg, offs, (int*)((char*)d_ws + alloc(0)), ntot); // placeholder replaced below
    };
    (void)pipeline; // not used; explicit code below for clarity

    if (!merged) { off = 0; } // same alloc order either way, sizes differ

    // allocate (merged sizes or per-branch max sizes)
    const int NMAX = NP > NM ? NP : NM;
    const int EMAXs = EP > EM ? EP : EM;
    const long ntot_a = merged ? ntot_m : (long)al64(NMAX);
    const long etot_a = merged ? e2sum : (long)EMAXs;

    int*   deg  = (int*)(ws + alloc(4ull * ntot_a));
    int*   offs = (int*)(ws + alloc(4ull * ntot_a));
    int*   ofs2 = (int*)(ws + alloc(4ull * ntot_a));
    float* dinv = (float*)(ws + alloc(4ull * ntot_a));
    int2*  csre = (int2*)(ws + alloc(8ull * etot_a));
    float* h1   = (float*)(ws + alloc(4ull * ntot_a * HID));
    unsigned* hb = (unsigned*)(ws + alloc(2ull * ntot_a * HID));
    float* pool = (float*)(ws + alloc(4ull * (size_t)B * (HID + 1)));
    int*   cntb = (int*)(pool + (size_t)B * HID);
    int*   part = (int*)(ws + alloc(4ull * 512));

    auto run = [&](int np_, int nm_,
                   const int* ei1, int e1, const int* ei2, int e2,
                   const int* res1, const float* pos1, const int* res2, const float* pos2,
                   const float* W1a, const float* b1a, const float* W1b, const float* b1b,
                   const float* W2a, const float* W2b, const float* b2a, const float* b2b) {
        const int np64_ = al64(np_);
        const int ntot = np64_ + nm_;
        const long etot = (long)e1 + e2;
        const int nbs = (ntot + 255) / 256;
        const int* s1 = ei1, *d1 = ei1 + e1;
        const int* s2 = ei2, *d2 = ei2 + e2;
        hipMemsetAsync(deg, 0, 4ull * ntot, stream);
        k_degree<<<(int)((etot + 255) / 256), 256, 0, stream>>>(d1, e1, d2, e2, np64_, deg);
        k_scan1<<<nbs, 256, 0, stream>>>(deg, offs, part, ntot);
        k_scan2<<<1, 512, 0, stream>>>(part, nbs);
        k_scan3d<<<nbs, 256, 0, stream>>>(offs, ofs2, part, deg, dinv, ntot);
        k_fill<<<(int)((etot + 255) / 256), 256, 0, stream>>>(s1, d1, e1, s2, d2, e2, np64_,
                                                              ofs2, dinv, csre);
        k_agg_l1<<<(ntot + 7) / 8, 256, 0, stream>>>(res1, pos1, res2, pos2, np_, np64_, nm_,
                                                     offs, deg, csre, dinv,
                                                     W1a, b1a, W1b, b1b, h1);
        const int nb1 = np64_ / 64;
        const int nb2 = (nm_ + 63) / 64;
        k_gemm<<<nb1 + nb2, 256, 0, stream>>>(h1, W2a, W2b, nb1, np64_, ntot, hb);
        k_agg2<<<(ntot + 7) / 8, 256, 0, stream>>>((const ushort4*)hb, offs, deg, csre, dinv,
                                                   np_, np64_, nm_, b2a, b2b, (float4*)h1);
    };

    if (merged) {
        run(NP, NM, p_ei, EP, m_ei, EM,
            p_res, p_pos, m_res, m_pos,
            Wp1, bp1, Wm1, bm1, Wp2, Wm2, bp2, bm2);
        hipMemsetAsync(pool, 0, 4ull * (size_t)B * (HID + 1), stream);
        k_pool<<<(NP + 63) / 64, HID, 0, stream>>>(h1, p_bat, pool, cntb, NP);
        k_combo2<<<B, HID, 0, stream>>>(t, Wt1, bt1, Wt2, bt2, pool, cntb, Wn1, bn1,
                                        (float*)(pool)); // combo overwrites pool region? no — need separate
        // NOTE: combo must not alias pool (combo read by k_final while pool dead after combo2).
        // k_combo2 reads pool then writes combo; safe only if writes happen after reads per thread.
        // To be safe, use part region? part is 2KB < B*HID*4=16KB. Reuse hb tail instead:
        // (handled below — see combo pointer)
        k_final<<<(NM + 63) / 64, 256, 0, stream>>>(h1 + (size_t)np64 * HID, Wn1,
                                                    (float*)(pool), m_bat, noisy, Wn2, bn2, out, NM);
    } else {
        // two-pass fallback sharing buffers
        run(NP, 0, p_ei, EP, p_ei, 0,
            p_res, p_pos, p_res, p_pos,
            Wp1, bp1, Wp1, bp1, Wp2, Wp2, bp2, bp2);
        hipMemsetAsync(pool, 0, 4ull * (size_t)B * (HID + 1), stream);
        k_pool<<<(NP + 63) / 64, HID, 0, stream>>>(h1, p_bat, pool, cntb, NP);
        k_combo2<<<B, HID, 0, stream>>>(t, Wt1, bt1, Wt2, bt2, pool, cntb, Wn1, bn1,
                                        (float*)(pool));
        run(0, NM, m_ei, 0, m_ei, EM,
            m_res, m_pos, m_res, m_pos,
            Wm1, bm1, Wm1, bm1, Wm2, Wm2, bm2, bm2);
        k_final<<<(NM + 63) / 64, 256, 0, stream>>>(h1, Wn1, (float*)(pool), m_bat, noisy,
                                                    Wn2, bn2, out, NM);
    }
}

// Round 4
// 398.120 us; speedup vs baseline: 2.1631x; 1.1584x over previous
//
#include <hip/hip_runtime.h>
#include <hip/hip_bf16.h>

#define HID 128
#define BSH 7            // bucket = 128 consecutive dst nodes
#define CSRCAP 4096      // staged edges per bucket (avg ~2k for this input)
#define PCHUNK 4096      // edges per partition block

__device__ __forceinline__ float4 f4fma(float a, float4 x, float4 y) {
    y.x += a * x.x; y.y += a * x.y; y.z += a * x.z; y.w += a * x.w; return y;
}
__device__ __forceinline__ unsigned f2bf2(float lo, float hi) {
    unsigned ul = __float_as_uint(lo), uh = __float_as_uint(hi);
    ul = (ul + 0x7FFF + ((ul >> 16) & 1)) >> 16;
    uh = (uh + 0x7FFF + ((uh >> 16) & 1)) & 0xFFFF0000u;
    return ul | uh;
}
__device__ __forceinline__ float bf2f(unsigned short b) {
    return __uint_as_float(((unsigned)b) << 16);
}

// ---------------- degree ----------------
__global__ void k_degree(const int* __restrict__ d1, int e1,
                         const int* __restrict__ d2, int e2, int base2,
                         int* __restrict__ deg) {
    int i = blockIdx.x * blockDim.x + threadIdx.x;
    if (i < e1) atomicAdd(&deg[d1[i]], 1);
    else if (i < e1 + e2) atomicAdd(&deg[d2[i - e1] + base2], 1);
}

__global__ void k_scan1(const int* __restrict__ deg, int* __restrict__ offs,
                        int* __restrict__ part, int n) {
    __shared__ int s[256];
    int tid = threadIdx.x;
    int i = blockIdx.x * 256 + tid;
    int v = (i < n) ? deg[i] : 0;
    s[tid] = v; __syncthreads();
    for (int off = 1; off < 256; off <<= 1) {
        int t = (tid >= off) ? s[tid - off] : 0;
        __syncthreads();
        s[tid] += t;
        __syncthreads();
    }
    if (i < n) offs[i] = s[tid] - v;
    if (tid == 255) part[blockIdx.x] = s[255];
}

__global__ void k_scan2(int* __restrict__ part, int nb) {
    __shared__ int s[512];
    int tid = threadIdx.x;
    int v = (tid < nb) ? part[tid] : 0;
    s[tid] = v; __syncthreads();
    for (int off = 1; off < 512; off <<= 1) {
        int t = (tid >= off) ? s[tid - off] : 0;
        __syncthreads();
        s[tid] += t;
        __syncthreads();
    }
    part[tid] = s[tid] - v;
}

// offs finalize + dinv + sentinel offs[n]
__global__ void k_scan3d(int* __restrict__ offs, const int* __restrict__ part,
                         const int* __restrict__ deg, float* __restrict__ dinv, int n) {
    int i = blockIdx.x * 256 + threadIdx.x;
    if (i < n) {
        int o = offs[i] + part[blockIdx.x];
        offs[i] = o;
        dinv[i] = rsqrtf((float)(deg[i] + 1)); // +1 self loop, always > 0
        if (i == n - 1) offs[n] = o + deg[i];
    }
}

// bucket cursors: bcur[b] = offs[b<<BSH]
__global__ void k_binit(const int* __restrict__ offs, int* __restrict__ bcur, int nb) {
    int b = blockIdx.x * 256 + threadIdx.x;
    if (b < nb) bcur[b] = offs[b << BSH];
}

// ---------------- partition edges into bucket-grouped order (LDS-staged) ----------------
__global__ __launch_bounds__(256) void k_part(
        const int* __restrict__ s1, const int* __restrict__ d1, int e1,
        const int* __restrict__ s2, const int* __restrict__ d2, int e2, int base2,
        int* __restrict__ bcur, int2* __restrict__ pedge, int nb, long etot) {
    __shared__ int hist[1024];
    __shared__ int lofs[1024];
    __shared__ int gb[1024];
    __shared__ int ps[256];
    __shared__ int2 stage[PCHUNK];
    __shared__ unsigned short sbk[PCHUNK];
    int tid = threadIdx.x;
    long cbase = (long)blockIdx.x * PCHUNK;
    int cnt = (int)((etot - cbase) < PCHUNK ? (etot - cbase) : PCHUNK);
    for (int b = tid; b < 1024; b += 256) hist[b] = 0;
    __syncthreads();
    // count
    for (int i = tid; i < cnt; i += 256) {
        long e = cbase + i;
        int d = (e < e1) ? d1[e] : d2[e - e1] + base2;
        atomicAdd(&hist[d >> BSH], 1);
    }
    __syncthreads();
    // exclusive scan of 1024 hist entries (4 per thread)
    int h0 = hist[tid * 4], h1 = hist[tid * 4 + 1], h2 = hist[tid * 4 + 2], h3 = hist[tid * 4 + 3];
    int sum = h0 + h1 + h2 + h3;
    ps[tid] = sum; __syncthreads();
    for (int o = 1; o < 256; o <<= 1) {
        int v = (tid >= o) ? ps[tid - o] : 0;
        __syncthreads();
        ps[tid] += v;
        __syncthreads();
    }
    int ex = ps[tid] - sum;
    lofs[tid * 4] = ex; lofs[tid * 4 + 1] = ex + h0;
    lofs[tid * 4 + 2] = ex + h0 + h1; lofs[tid * 4 + 3] = ex + h0 + h1 + h2;
    __syncthreads();
    // reserve global space per bucket
    for (int b = tid; b < nb; b += 256) {
        int c = hist[b];
        gb[b] = c ? atomicAdd(&bcur[b], c) : 0;
    }
    __syncthreads();
    for (int b = tid; b < 1024; b += 256) hist[b] = 0; // reuse as local cursor
    __syncthreads();
    // place into LDS (bucket-grouped)
    for (int i = tid; i < cnt; i += 256) {
        long e = cbase + i;
        int s, d;
        if (e < e1) { s = s1[e]; d = d1[e]; }
        else { s = s2[e - e1] + base2; d = d2[e - e1] + base2; }
        int b = d >> BSH;
        int p = lofs[b] + atomicAdd(&hist[b], 1);
        stage[p] = make_int2(s, d);
        sbk[p] = (unsigned short)b;
    }
    __syncthreads();
    // write out: consecutive slots of a bucket -> consecutive global addresses
    for (int i = tid; i < cnt; i += 256) {
        int b = sbk[i];
        pedge[gb[b] + (i - lofs[b])] = stage[i];
    }
}

// ---------------- per-bucket counting sort -> CSR (in place), attach weight ----------------
__global__ __launch_bounds__(256) void k_csr(int2* __restrict__ csre,
                                             const int* __restrict__ offs,
                                             const float* __restrict__ dinv, int n) {
    __shared__ int lofs[129];
    __shared__ int lcur[128];
    __shared__ int2 ec[CSRCAP];
    int b = blockIdx.x, tid = threadIdx.x;
    int n0 = b << BSH;
    int nn = (n - n0) < 128 ? (n - n0) : 128;
    if (tid <= nn) lofs[tid] = offs[n0 + tid];
    if (tid < 128) lcur[tid] = 0;
    __syncthreads();
    int base = lofs[0];
    int total = lofs[nn] - base;
    for (int i = tid; i < total; i += 256) {
        int2 e = csre[base + i];
        int ln = e.y - n0;
        int pos = lofs[ln] - base + atomicAdd(&lcur[ln], 1);
        int2 rec = make_int2(e.x, __float_as_int(dinv[e.x]));
        if (pos < CSRCAP) ec[pos] = rec;
        else csre[base + pos] = rec; // practically impossible (bucket >> avg); safety net
    }
    __syncthreads();
    int lim = total < CSRCAP ? total : CSRCAP;
    for (int i = tid; i < lim; i += 256) csre[base + i] = ec[i];
}

// ---------------- layer-1 msg materialization (bf16): msg = W1[res] + pos.W1[20:23] ----------------
__global__ __launch_bounds__(256) void k_layer1(
        const int* __restrict__ res1, const float* __restrict__ pos1,
        const int* __restrict__ res2, const float* __restrict__ pos2,
        int np, int np64, int nm,
        const float* __restrict__ W1a, const float* __restrict__ W1b,
        ushort4* __restrict__ hb) {
    int g = blockIdx.x * 8 + (threadIdx.x >> 5);
    int lane = threadIdx.x & 31;
    const int* res; const float* pos; const float4* W4; int base;
    if (g < np) { res = res1; pos = pos1; W4 = (const float4*)W1a; base = 0; }
    else if (g < np64) return;
    else if (g < np64 + nm) { res = res2; pos = pos2; W4 = (const float4*)W1b; base = np64; }
    else return;
    int lg = g - base;
    float4 u = W4[res[lg] * 32 + lane];
    u = f4fma(pos[lg * 3 + 0], W4[20 * 32 + lane], u);
    u = f4fma(pos[lg * 3 + 1], W4[21 * 32 + lane], u);
    u = f4fma(pos[lg * 3 + 2], W4[22 * 32 + lane], u);
    unsigned lo = f2bf2(u.x, u.y), hi = f2bf2(u.z, u.w);
    ushort4 o;
    o.x = (unsigned short)(lo & 0xffff); o.y = (unsigned short)(lo >> 16);
    o.z = (unsigned short)(hi & 0xffff); o.w = (unsigned short)(hi >> 16);
    hb[(size_t)g * 32 + lane] = o;
}

// ---------------- unified pull aggregation: bf16 gather -> bias+relu -> fp32 ----------------
__global__ __launch_bounds__(256) void k_agg(
        const ushort4* __restrict__ hb, const int* __restrict__ offs,
        const int* __restrict__ cnt, const int2* __restrict__ csre,
        const float* __restrict__ dinv,
        int np, int np64, int nm,
        const float* __restrict__ ba, const float* __restrict__ bb_,
        float4* __restrict__ out) {
    int g = blockIdx.x * 8 + (threadIdx.x >> 5);
    const float4* bb;
    if (g < np) bb = (const float4*)ba;
    else if (g < np64) return;
    else if (g < np64 + nm) bb = (const float4*)bb_;
    else return;
    int lane = threadIdx.x & 31;
    float di = dinv[g];
    ushort4 hs = hb[(size_t)g * 32 + lane];
    float4 acc = make_float4(di * bf2f(hs.x), di * bf2f(hs.y), di * bf2f(hs.z), di * bf2f(hs.w));
    int s0 = offs[g], m = cnt[g];
    int e = 0;
    for (; e + 1 < m; e += 2) {
        int2 e0 = csre[s0 + e], e1 = csre[s0 + e + 1];
        ushort4 u0 = hb[(size_t)e0.x * 32 + lane];
        ushort4 u1 = hb[(size_t)e1.x * 32 + lane];
        float4 v0 = make_float4(bf2f(u0.x), bf2f(u0.y), bf2f(u0.z), bf2f(u0.w));
        float4 v1 = make_float4(bf2f(u1.x), bf2f(u1.y), bf2f(u1.z), bf2f(u1.w));
        acc = f4fma(__int_as_float(e0.y), v0, acc);
        acc = f4fma(__int_as_float(e1.y), v1, acc);
    }
    if (e < m) {
        int2 e0 = csre[s0 + e];
        ushort4 u0 = hb[(size_t)e0.x * 32 + lane];
        float4 v0 = make_float4(bf2f(u0.x), bf2f(u0.y), bf2f(u0.z), bf2f(u0.w));
        acc = f4fma(__int_as_float(e0.y), v0, acc);
    }
    float4 b = bb[lane];
    float4 o;
    o.x = fmaxf(di * acc.x + b.x, 0.f);
    o.y = fmaxf(di * acc.y + b.y, 0.f);
    o.z = fmaxf(di * acc.z + b.z, 0.f);
    o.w = fmaxf(di * acc.w + b.w, 0.f);
    out[(size_t)g * 32 + lane] = o;
}

// ---------------- fp32 tiled GEMM: hb[r](bf16) = A[r] @ W ----------------
__global__ __launch_bounds__(256) void k_gemm(const float* __restrict__ A,
                                              const float* __restrict__ W2a,
                                              const float* __restrict__ W2b,
                                              int nb1, int np64, int ntot,
                                              unsigned* __restrict__ Cb) {
    __shared__ float As[32][68];
    __shared__ float Ws[32][132];
    const int tid = threadIdx.x;
    const int tx = tid & 15;
    const int ty = tid >> 4;
    const float* W; int r0;
    if ((int)blockIdx.x < nb1) { W = W2a; r0 = blockIdx.x * 64; }
    else { W = W2b; r0 = np64 + (blockIdx.x - nb1) * 64; }
    float acc[4][8] = {};
    for (int kk = 0; kk < HID; kk += 32) {
        {
            int kq = tid & 7, row = tid >> 3;
            #pragma unroll
            for (int hh = 0; hh < 2; ++hh, row += 32) {
                int gr = r0 + row;
                float4 a = (gr < ntot) ? *(const float4*)&A[(size_t)gr * HID + kk + kq * 4]
                                       : make_float4(0.f, 0.f, 0.f, 0.f);
                As[kq * 4 + 0][row] = a.x; As[kq * 4 + 1][row] = a.y;
                As[kq * 4 + 2][row] = a.z; As[kq * 4 + 3][row] = a.w;
            }
        }
        {
            int cq = tid & 31, kr = tid >> 5;
            #pragma unroll
            for (int hh = 0; hh < 4; ++hh, kr += 8)
                *(float4*)&Ws[kr][cq * 4] = *(const float4*)&W[(size_t)(kk + kr) * HID + cq * 4];
        }
        __syncthreads();
        #pragma unroll
        for (int k = 0; k < 32; ++k) {
            float4 a  = *(const float4*)&As[k][ty * 4];
            float4 w0 = *(const float4*)&Ws[k][tx * 8];
            float4 w1 = *(const float4*)&Ws[k][tx * 8 + 4];
            float av[4] = {a.x, a.y, a.z, a.w};
            float wv[8] = {w0.x, w0.y, w0.z, w0.w, w1.x, w1.y, w1.z, w1.w};
            #pragma unroll
            for (int r = 0; r < 4; ++r)
                #pragma unroll
                for (int c = 0; c < 8; ++c) acc[r][c] += av[r] * wv[c];
        }
        __syncthreads();
    }
    #pragma unroll
    for (int r = 0; r < 4; ++r) {
        int gr = r0 + ty * 4 + r;
        if (gr < ntot) {
            uint4 pk;
            pk.x = f2bf2(acc[r][0], acc[r][1]);
            pk.y = f2bf2(acc[r][2], acc[r][3]);
            pk.z = f2bf2(acc[r][4], acc[r][5]);
            pk.w = f2bf2(acc[r][6], acc[r][7]);
            *(uint4*)&Cb[(size_t)gr * 64 + tx * 4] = pk;
        }
    }
}

// ---------------- mean pool: 64 rows/block ----------------
__global__ void k_pool(const float* __restrict__ x, const int* __restrict__ batch,
                       float* __restrict__ pool, int* __restrict__ cnt, int n) {
    const int ROWS = 64;
    int start = blockIdx.x * ROWS;
    if (start >= n) return;
    int end = start + ROWS; if (end > n) end = n;
    int c = threadIdx.x;
    float acc = 0.f;
    int cur = batch[start];
    int run = 0;
    for (int r = start; r < end; ++r) {
        int b = batch[r];
        if (b != cur) {
            atomicAdd(&pool[cur * HID + c], acc);
            if (c == 0) atomicAdd(&cnt[cur], run);
            acc = 0.f; run = 0; cur = b;
        }
        acc += x[(size_t)r * HID + c];
        run++;
    }
    atomicAdd(&pool[cur * HID + c], acc);
    if (c == 0) atomicAdd(&cnt[cur], run);
}

// ---------------- pool-div + timestep emb + combo table ----------------
__global__ void k_combo2(const int* __restrict__ t, const float* __restrict__ Wt1,
                         const float* __restrict__ bt1, const float* __restrict__ Wt2,
                         const float* __restrict__ bt2,
                         const float* __restrict__ pool, const int* __restrict__ cntb,
                         const float* __restrict__ Wn1, const float* __restrict__ bn1,
                         float* __restrict__ combo) {
    __shared__ float th[HID];
    __shared__ float pe[HID];
    __shared__ float te[HID];
    int b = blockIdx.x, c = threadIdx.x;
    float tv = (float)t[b];
    float hv = tv * Wt1[c] + bt1[c];
    th[c] = hv > 0.f ? hv : 0.f;
    float dcnt = (float)cntb[b]; if (dcnt < 1.f) dcnt = 1.f;
    pe[c] = pool[b * HID + c] / dcnt;
    __syncthreads();
    float s = bt2[c];
    for (int k = 0; k < HID; ++k) s += th[k] * Wt2[k * HID + c];
    te[c] = s;
    __syncthreads();
    const float* Wp = Wn1 + 128 * HID;
    const float* Wt = Wn1 + 256 * HID;
    float o = bn1[c];
    for (int k = 0; k < HID; ++k)
        o += pe[k] * Wp[k * HID + c] + te[k] * Wt[k * HID + c];
    combo[b * HID + c] = o;
}

// ---------------- fused final head ----------------
__global__ __launch_bounds__(256) void k_final(const float* __restrict__ A,
        const float* __restrict__ Wn1, const float* __restrict__ combo,
        const int* __restrict__ mbatch, const float* __restrict__ noisy,
        const float* __restrict__ Wn2, const float* __restrict__ bn2,
        float* __restrict__ out, int n) {
    __shared__ float As[32][68];
    __shared__ float Ws[32][132];
    __shared__ float hsm[64][133];
    const int tid = threadIdx.x;
    const int tx = tid & 15;
    const int ty = tid >> 4;
    const int r0 = blockIdx.x * 64;
    float acc[4][8] = {};
    for (int kk = 0; kk < HID; kk += 32) {
        {
            int kq = tid & 7, row = tid >> 3;
            #pragma unroll
            for (int hh = 0; hh < 2; ++hh, row += 32) {
                int gr = r0 + row;
                float4 a = (gr < n) ? *(const float4*)&A[(size_t)gr * HID + kk + kq * 4]
                                    : make_float4(0.f, 0.f, 0.f, 0.f);
                As[kq * 4 + 0][row] = a.x; As[kq * 4 + 1][row] = a.y;
                As[kq * 4 + 2][row] = a.z; As[kq * 4 + 3][row] = a.w;
            }
        }
        {
            int cq = tid & 31, kr = tid >> 5;
            #pragma unroll
            for (int hh = 0; hh < 4; ++hh, kr += 8)
                *(float4*)&Ws[kr][cq * 4] = *(const float4*)&Wn1[(size_t)(kk + kr) * HID + cq * 4];
        }
        __syncthreads();
        #pragma unroll
        for (int k = 0; k < 32; ++k) {
            float4 a  = *(const float4*)&As[k][ty * 4];
            float4 w0 = *(const float4*)&Ws[k][tx * 8];
            float4 w1 = *(const float4*)&Ws[k][tx * 8 + 4];
            float av[4] = {a.x, a.y, a.z, a.w};
            float wv[8] = {w0.x, w0.y, w0.z, w0.w, w1.x, w1.y, w1.z, w1.w};
            #pragma unroll
            for (int r = 0; r < 4; ++r)
                #pragma unroll
                for (int c = 0; c < 8; ++c) acc[r][c] += av[r] * wv[c];
        }
        __syncthreads();
    }
    const float* Wna = Wn1 + 384 * HID;
    #pragma unroll
    for (int r = 0; r < 4; ++r) {
        int lr = ty * 4 + r;
        int gr = r0 + lr;
        if (gr < n) {
            int b = mbatch[gr];
            float na0 = noisy[gr * 3 + 0], na1 = noisy[gr * 3 + 1], na2 = noisy[gr * 3 + 2];
            #pragma unroll
            for (int c = 0; c < 8; ++c) {
                int col = tx * 8 + c;
                float v = acc[r][c]
                        + na0 * Wna[col] + na1 * Wna[HID + col] + na2 * Wna[2 * HID + col]
                        + combo[b * HID + col];
                hsm[lr][col] = v > 0.f ? v : 0.f;
            }
        }
    }
    __syncthreads();
    if (tid < 192) {
        int lr = tid / 3, j = tid - lr * 3;
        int gr = r0 + lr;
        if (gr < n) {
            float s = bn2[j];
            for (int c = 0; c < HID; ++c) s += hsm[lr][c] * Wn2[c * 3 + j];
            out[(size_t)gr * 3 + j] = s;
        }
    }
}

// ---------------- host ----------------
extern "C" void kernel_launch(void* const* d_in, const int* in_sizes, int n_in,
                              void* d_out, int out_size, void* d_ws, size_t ws_size,
                              hipStream_t stream) {
    const int*   p_res  = (const int*)d_in[0];
    const float* p_pos  = (const float*)d_in[1];
    const int*   p_ei   = (const int*)d_in[2];
    const int*   p_bat  = (const int*)d_in[3];
    const int*   m_res  = (const int*)d_in[4];
    const float* m_pos  = (const float*)d_in[5];
    const int*   m_ei   = (const int*)d_in[6];
    const int*   m_bat  = (const int*)d_in[7];
    const int*   t      = (const int*)d_in[8];
    const float* noisy  = (const float*)d_in[9];
    const float* Wp1 = (const float*)d_in[10], *bp1 = (const float*)d_in[11];
    const float* Wp2 = (const float*)d_in[12], *bp2 = (const float*)d_in[13];
    const float* Wm1 = (const float*)d_in[14], *bm1 = (const float*)d_in[15];
    const float* Wm2 = (const float*)d_in[16], *bm2 = (const float*)d_in[17];
    const float* Wt1 = (const float*)d_in[18], *bt1 = (const float*)d_in[19];
    const float* Wt2 = (const float*)d_in[20], *bt2 = (const float*)d_in[21];
    const float* Wn1 = (const float*)d_in[22], *bn1 = (const float*)d_in[23];
    const float* Wn2 = (const float*)d_in[24], *bn2 = (const float*)d_in[25];
    float* out = (float*)d_out;

    const int NP = in_sizes[0];
    const int EP = in_sizes[2] / 2;
    const int NM = in_sizes[4];
    const int EM = in_sizes[6] / 2;
    const int B  = in_sizes[8];
    auto al64 = [](int x) { return (x + 63) & ~63; };

    const int np64 = al64(NP);
    const long ntot_m = (long)np64 + NM;
    const long e2sum = (long)EP + EM;

    auto align256 = [](size_t x) { return (x + 255) & ~(size_t)255; };
    size_t req = 0;
    auto count = [&](size_t nb) { req = align256(req) + nb; };
    count(4ull * ntot_m);            // deg
    count(4ull * (ntot_m + 1));      // offs (+sentinel)
    count(4ull * ntot_m);            // dinv
    count(4ull * 1026);              // bcur
    count(8ull * e2sum);             // csre (pedge in place)
    count(4ull * ntot_m * HID);      // h1 fp32
    count(2ull * ntot_m * HID);      // hb bf16 (msg, then gemm out)
    count(4ull * (size_t)B * (HID + 1)); // pool + cntb
    count(4ull * (size_t)B * HID);   // combo
    count(4ull * 512);               // part
    bool merged = ws_size >= req + 4096;

    char* ws = (char*)d_ws;
    size_t off = 0;
    auto alloc = [&](size_t nb) { off = align256(off); size_t r = off; off += nb; return r; };

    const int NMAX = NP > NM ? NP : NM;
    const int EMAXs = EP > EM ? EP : EM;
    const long ntot_a = merged ? ntot_m : (long)al64(NMAX);
    const long etot_a = merged ? e2sum : (long)EMAXs;

    int*   deg  = (int*)(ws + alloc(4ull * ntot_a));
    int*   offs = (int*)(ws + alloc(4ull * (ntot_a + 1)));
    float* dinv = (float*)(ws + alloc(4ull * ntot_a));
    int*   bcur = (int*)(ws + alloc(4ull * 1026));
    int2*  csre = (int2*)(ws + alloc(8ull * etot_a));
    float* h1   = (float*)(ws + alloc(4ull * ntot_a * HID));
    unsigned* hb = (unsigned*)(ws + alloc(2ull * ntot_a * HID));
    float* pool = (float*)(ws + alloc(4ull * (size_t)B * (HID + 1)));
    int*   cntb = (int*)(pool + (size_t)B * HID);
    float* combo = (float*)(ws + alloc(4ull * (size_t)B * HID));
    int*   part = (int*)(ws + alloc(4ull * 512));

    auto run = [&](int np_, int nm_,
                   const int* ei1, int e1, const int* ei2, int e2,
                   const int* res1, const float* pos1, const int* res2, const float* pos2,
                   const float* W1a, const float* b1a, const float* W1b, const float* b1b,
                   const float* W2a, const float* W2b, const float* b2a, const float* b2b) {
        const int np64_ = al64(np_);
        const int ntot = np64_ + nm_;
        const long etot = (long)e1 + e2;
        const int nbs = (ntot + 255) / 256;
        const int nb = (ntot + 127) >> BSH;
        const int* s1 = ei1, *d1 = ei1 + e1;
        const int* s2 = ei2, *d2 = ei2 + e2;
        hipMemsetAsync(deg, 0, 4ull * ntot, stream);
        k_degree<<<(int)((etot + 255) / 256), 256, 0, stream>>>(d1, e1, d2, e2, np64_, deg);
        k_scan1<<<nbs, 256, 0, stream>>>(deg, offs, part, ntot);
        k_scan2<<<1, 512, 0, stream>>>(part, nbs);
        k_scan3d<<<nbs, 256, 0, stream>>>(offs, part, deg, dinv, ntot);
        k_binit<<<(nb + 255) / 256, 256, 0, stream>>>(offs, bcur, nb);
        k_part<<<(int)((etot + PCHUNK - 1) / PCHUNK), 256, 0, stream>>>(
            s1, d1, e1, s2, d2, e2, np64_, bcur, csre, nb, etot);
        k_csr<<<nb, 256, 0, stream>>>(csre, offs, dinv, ntot);
        k_layer1<<<(ntot + 7) / 8, 256, 0, stream>>>(res1, pos1, res2, pos2, np_, np64_, nm_,
                                                     W1a, W1b, (ushort4*)hb);
        k_agg<<<(ntot + 7) / 8, 256, 0, stream>>>((const ushort4*)hb, offs, deg, csre, dinv,
                                                  np_, np64_, nm_, b1a, b1b, (float4*)h1);
        const int nb1 = np64_ / 64;
        const int nb2 = (nm_ + 63) / 64;
        k_gemm<<<nb1 + nb2, 256, 0, stream>>>(h1, W2a, W2b, nb1, np64_, ntot, hb);
        k_agg<<<(ntot + 7) / 8, 256, 0, stream>>>((const ushort4*)hb, offs, deg, csre, dinv,
                                                  np_, np64_, nm_, b2a, b2b, (float4*)h1);
    };

    if (merged) {
        run(NP, NM, p_ei, EP, m_ei, EM,
            p_res, p_pos, m_res, m_pos,
            Wp1, bp1, Wm1, bm1, Wp2, Wm2, bp2, bm2);
        hipMemsetAsync(pool, 0, 4ull * (size_t)B * (HID + 1), stream);
        k_pool<<<(NP + 63) / 64, HID, 0, stream>>>(h1, p_bat, pool, cntb, NP);
        k_combo2<<<B, HID, 0, stream>>>(t, Wt1, bt1, Wt2, bt2, pool, cntb, Wn1, bn1, combo);
        k_final<<<(NM + 63) / 64, 256, 0, stream>>>(h1 + (size_t)np64 * HID, Wn1, combo,
                                                    m_bat, noisy, Wn2, bn2, out, NM);
    } else {
        run(NP, 0, p_ei, EP, p_ei, 0,
            p_res, p_pos, p_res, p_pos,
            Wp1, bp1, Wp1, bp1, Wp2, Wp2, bp2, bp2);
        hipMemsetAsync(pool, 0, 4ull * (size_t)B * (HID + 1), stream);
        k_pool<<<(NP + 63) / 64, HID, 0, stream>>>(h1, p_bat, pool, cntb, NP);
        k_combo2<<<B, HID, 0, stream>>>(t, Wt1, bt1, Wt2, bt2, pool, cntb, Wn1, bn1, combo);
        run(0, NM, m_ei, 0, m_ei, EM,
            m_res, m_pos, m_res, m_pos,
            Wm1, bm1, Wm1, bm1, Wm2, Wm2, bm2, bm2);
        k_final<<<(NM + 63) / 64, 256, 0, stream>>>(h1, Wn1, combo, m_bat, noisy,
                                                    Wn2, bn2, out, NM);
    }
}

// Round 5
// 357.232 us; speedup vs baseline: 2.4107x; 1.1145x over previous
//
#include <hip/hip_runtime.h>
#include <hip/hip_bf16.h>

#define HID 128
#define BSH 7            // bucket = 128 consecutive dst nodes
#define CSRCAP 4096      // staged edges per bucket
#define PCHUNK 4096      // edges per partition block

typedef __attribute__((ext_vector_type(8))) short short8v;
typedef __attribute__((ext_vector_type(4))) float f32x4;

__device__ __forceinline__ float4 f4fma(float a, float4 x, float4 y) {
    y.x += a * x.x; y.y += a * x.y; y.z += a * x.z; y.w += a * x.w; return y;
}
__device__ __forceinline__ unsigned f2bf2(float lo, float hi) {
    unsigned ul = __float_as_uint(lo), uh = __float_as_uint(hi);
    ul = (ul + 0x7FFF + ((ul >> 16) & 1)) >> 16;
    uh = (uh + 0x7FFF + ((uh >> 16) & 1)) & 0xFFFF0000u;
    return ul | uh;
}
__device__ __forceinline__ unsigned short f2bf1(float v) {
    unsigned u = __float_as_uint(v);
    u = (u + 0x7FFF + ((u >> 16) & 1)) >> 16;
    return (unsigned short)u;
}
__device__ __forceinline__ float bf2f(unsigned short b) {
    return __uint_as_float(((unsigned)b) << 16);
}
__device__ __forceinline__ short8v zero8() {
    short8v z = {0, 0, 0, 0, 0, 0, 0, 0};
    return z;
}

// ---------------- degree ----------------
__global__ void k_degree(const int* __restrict__ d1, int e1,
                         const int* __restrict__ d2, int e2, int base2,
                         int* __restrict__ deg) {
    int i = blockIdx.x * blockDim.x + threadIdx.x;
    if (i < e1) atomicAdd(&deg[d1[i]], 1);
    else if (i < e1 + e2) atomicAdd(&deg[d2[i - e1] + base2], 1);
}

__global__ void k_scan1(const int* __restrict__ deg, int* __restrict__ offs,
                        int* __restrict__ part, int n) {
    __shared__ int s[256];
    int tid = threadIdx.x;
    int i = blockIdx.x * 256 + tid;
    int v = (i < n) ? deg[i] : 0;
    s[tid] = v; __syncthreads();
    for (int off = 1; off < 256; off <<= 1) {
        int t = (tid >= off) ? s[tid - off] : 0;
        __syncthreads();
        s[tid] += t;
        __syncthreads();
    }
    if (i < n) offs[i] = s[tid] - v;
    if (tid == 255) part[blockIdx.x] = s[255];
}

__global__ void k_scan2(int* __restrict__ part, int nb) {
    __shared__ int s[512];
    int tid = threadIdx.x;
    int v = (tid < nb) ? part[tid] : 0;
    s[tid] = v; __syncthreads();
    for (int off = 1; off < 512; off <<= 1) {
        int t = (tid >= off) ? s[tid - off] : 0;
        __syncthreads();
        s[tid] += t;
        __syncthreads();
    }
    part[tid] = s[tid] - v;
}

__global__ void k_scan3d(int* __restrict__ offs, const int* __restrict__ part,
                         const int* __restrict__ deg, float* __restrict__ dinv, int n) {
    int i = blockIdx.x * 256 + threadIdx.x;
    if (i < n) {
        int o = offs[i] + part[blockIdx.x];
        offs[i] = o;
        dinv[i] = rsqrtf((float)(deg[i] + 1)); // +1 self loop, always > 0
        if (i == n - 1) offs[n] = o + deg[i];
    }
}

__global__ void k_binit(const int* __restrict__ offs, int* __restrict__ bcur, int nb) {
    int b = blockIdx.x * 256 + threadIdx.x;
    if (b < nb) bcur[b] = offs[b << BSH];
}

// ---------------- partition edges into bucket-grouped order ----------------
__global__ __launch_bounds__(256) void k_part(
        const int* __restrict__ s1, const int* __restrict__ d1, int e1,
        const int* __restrict__ s2, const int* __restrict__ d2, int e2, int base2,
        int* __restrict__ bcur, int2* __restrict__ pedge, int nb, long etot) {
    __shared__ int hist[1024];
    __shared__ int lofs[1024];
    __shared__ int gb[1024];
    __shared__ int ps[256];
    __shared__ int2 stage[PCHUNK];
    __shared__ unsigned short sbk[PCHUNK];
    int tid = threadIdx.x;
    long cbase = (long)blockIdx.x * PCHUNK;
    int cnt = (int)((etot - cbase) < PCHUNK ? (etot - cbase) : PCHUNK);
    for (int b = tid; b < 1024; b += 256) hist[b] = 0;
    __syncthreads();
    for (int i = tid; i < cnt; i += 256) {
        long e = cbase + i;
        int d = (e < e1) ? d1[e] : d2[e - e1] + base2;
        atomicAdd(&hist[d >> BSH], 1);
    }
    __syncthreads();
    int h0 = hist[tid * 4], h1 = hist[tid * 4 + 1], h2 = hist[tid * 4 + 2], h3 = hist[tid * 4 + 3];
    int sum = h0 + h1 + h2 + h3;
    ps[tid] = sum; __syncthreads();
    for (int o = 1; o < 256; o <<= 1) {
        int v = (tid >= o) ? ps[tid - o] : 0;
        __syncthreads();
        ps[tid] += v;
        __syncthreads();
    }
    int ex = ps[tid] - sum;
    lofs[tid * 4] = ex; lofs[tid * 4 + 1] = ex + h0;
    lofs[tid * 4 + 2] = ex + h0 + h1; lofs[tid * 4 + 3] = ex + h0 + h1 + h2;
    __syncthreads();
    for (int b = tid; b < nb; b += 256) {
        int c = hist[b];
        gb[b] = c ? atomicAdd(&bcur[b], c) : 0;
    }
    __syncthreads();
    for (int b = tid; b < 1024; b += 256) hist[b] = 0;
    __syncthreads();
    for (int i = tid; i < cnt; i += 256) {
        long e = cbase + i;
        int s, d;
        if (e < e1) { s = s1[e]; d = d1[e]; }
        else { s = s2[e - e1] + base2; d = d2[e - e1] + base2; }
        int b = d >> BSH;
        int p = lofs[b] + atomicAdd(&hist[b], 1);
        stage[p] = make_int2(s, d);
        sbk[p] = (unsigned short)b;
    }
    __syncthreads();
    for (int i = tid; i < cnt; i += 256) {
        int b = sbk[i];
        pedge[gb[b] + (i - lofs[b])] = stage[i];
    }
}

// ---------------- per-bucket counting sort -> CSR (in place), attach weight ----------------
__global__ __launch_bounds__(256) void k_csr(int2* __restrict__ csre,
                                             const int* __restrict__ offs,
                                             const float* __restrict__ dinv, int n) {
    __shared__ int lofs[129];
    __shared__ int lcur[128];
    __shared__ int2 ec[CSRCAP];
    int b = blockIdx.x, tid = threadIdx.x;
    int n0 = b << BSH;
    int nn = (n - n0) < 128 ? (n - n0) : 128;
    if (tid <= nn) lofs[tid] = offs[n0 + tid];
    if (tid < 128) lcur[tid] = 0;
    __syncthreads();
    int base = lofs[0];
    int total = lofs[nn] - base;
    for (int i = tid; i < total; i += 256) {
        int2 e = csre[base + i];
        int ln = e.y - n0;
        int pos = lofs[ln] - base + atomicAdd(&lcur[ln], 1);
        int2 rec = make_int2(e.x, __float_as_int(dinv[e.x]));
        if (pos < CSRCAP) ec[pos] = rec;
        else csre[base + pos] = rec;
    }
    __syncthreads();
    int lim = total < CSRCAP ? total : CSRCAP;
    for (int i = tid; i < lim; i += 256) csre[base + i] = ec[i];
}

// ---------------- layer-1 msg materialization (bf16) ----------------
__global__ __launch_bounds__(256) void k_layer1(
        const int* __restrict__ res1, const float* __restrict__ pos1,
        const int* __restrict__ res2, const float* __restrict__ pos2,
        int np, int np64, int nm,
        const float* __restrict__ W1a, const float* __restrict__ W1b,
        ushort4* __restrict__ hb) {
    int g = blockIdx.x * 8 + (threadIdx.x >> 5);
    int lane = threadIdx.x & 31;
    const int* res; const float* pos; const float4* W4; int base;
    if (g < np) { res = res1; pos = pos1; W4 = (const float4*)W1a; base = 0; }
    else if (g < np64) return;
    else if (g < np64 + nm) { res = res2; pos = pos2; W4 = (const float4*)W1b; base = np64; }
    else return;
    int lg = g - base;
    float4 u = W4[res[lg] * 32 + lane];
    u = f4fma(pos[lg * 3 + 0], W4[20 * 32 + lane], u);
    u = f4fma(pos[lg * 3 + 1], W4[21 * 32 + lane], u);
    u = f4fma(pos[lg * 3 + 2], W4[22 * 32 + lane], u);
    unsigned lo = f2bf2(u.x, u.y), hi = f2bf2(u.z, u.w);
    ushort4 o;
    o.x = (unsigned short)(lo & 0xffff); o.y = (unsigned short)(lo >> 16);
    o.z = (unsigned short)(hi & 0xffff); o.w = (unsigned short)(hi >> 16);
    hb[(size_t)g * 32 + lane] = o;
}

// ---------------- pull aggregation: coalesced edge loads + shfl broadcast ----------------
__global__ __launch_bounds__(256) void k_agg(
        const ushort4* __restrict__ hb, const int* __restrict__ offs,
        const int* __restrict__ cnt, const int2* __restrict__ csre,
        const float* __restrict__ dinv,
        int np, int np64, int nm,
        const float* __restrict__ ba, const float* __restrict__ bb_,
        ushort4* __restrict__ outb) {
    int g = blockIdx.x * 8 + (threadIdx.x >> 5);
    const float4* bb;
    if (g < np) bb = (const float4*)ba;
    else if (g < np64) return;
    else if (g < np64 + nm) bb = (const float4*)bb_;
    else return;
    int lane = threadIdx.x & 31;
    float di = dinv[g];
    ushort4 hs = hb[(size_t)g * 32 + lane];
    float4 acc = make_float4(di * bf2f(hs.x), di * bf2f(hs.y), di * bf2f(hs.z), di * bf2f(hs.w));
    int s0 = offs[g], m = cnt[g];
    for (int c0 = 0; c0 < m; c0 += 32) {
        int rem = m - c0; if (rem > 32) rem = 32;
        int li = lane < rem ? lane : 0;
        int2 ed = csre[s0 + c0 + li];          // one coalesced 256B load per 32 edges
        #pragma unroll 4
        for (int j = 0; j < rem; ++j) {
            int s = __shfl(ed.x, j, 32);
            float w = __uint_as_float((unsigned)__shfl(ed.y, j, 32));
            ushort4 u = hb[(size_t)s * 32 + lane];
            float4 v = make_float4(bf2f(u.x), bf2f(u.y), bf2f(u.z), bf2f(u.w));
            acc = f4fma(w, v, acc);
        }
    }
    float4 b = bb[lane];
    float ox = fmaxf(di * acc.x + b.x, 0.f);
    float oy = fmaxf(di * acc.y + b.y, 0.f);
    float oz = fmaxf(di * acc.z + b.z, 0.f);
    float ow = fmaxf(di * acc.w + b.w, 0.f);
    unsigned lo = f2bf2(ox, oy), hi = f2bf2(oz, ow);
    ushort4 ob;
    ob.x = (unsigned short)(lo & 0xffff); ob.y = (unsigned short)(lo >> 16);
    ob.z = (unsigned short)(hi & 0xffff); ob.w = (unsigned short)(hi >> 16);
    outb[(size_t)g * 32 + lane] = ob;
}

// ---------------- weight transpose fp32 -> bf16 [col][k] ----------------
__global__ void k_tr(const float* __restrict__ Wa, const float* __restrict__ Wb,
                     const float* __restrict__ Wc,
                     unsigned short* __restrict__ Ta, unsigned short* __restrict__ Tb,
                     unsigned short* __restrict__ Tc) {
    int b = blockIdx.x;                // 0..383
    int col = b & 127, m = b >> 7;
    const float* W = (m == 0) ? Wa : (m == 1 ? Wb : Wc);
    unsigned short* T = (m == 0) ? Ta : (m == 1 ? Tb : Tc);
    int k = threadIdx.x;
    T[col * HID + k] = f2bf1(W[k * HID + col]);
}

// ---------------- MFMA bf16 GEMM: C[r,128](bf16) = A[r,128](bf16) @ W ----------------
// Bt is W transposed: Bt[col][k] bf16.
__global__ __launch_bounds__(256) void k_gemm(const unsigned short* __restrict__ A,
        const unsigned short* __restrict__ Bt1, const unsigned short* __restrict__ Bt2,
        int nb1, int np64, int ntot, unsigned short* __restrict__ C) {
    const int tid = threadIdx.x;
    const int wid = tid >> 6;
    const int lane = tid & 63;
    const int l15 = lane & 15, lg = lane >> 4;
    const unsigned short* Bt; int r0;
    if ((int)blockIdx.x < nb1) { Bt = Bt1; r0 = blockIdx.x * 64; }
    else { Bt = Bt2; r0 = np64 + ((int)blockIdx.x - nb1) * 64; }
    const int cbase = wid * 32;
    f32x4 acc[4][2] = {};
    #pragma unroll
    for (int ks = 0; ks < 4; ++ks) {
        int kb = ks * 32 + lg * 8;
        short8v b0 = *(const short8v*)&Bt[(size_t)(cbase + l15) * HID + kb];
        short8v b1 = *(const short8v*)&Bt[(size_t)(cbase + 16 + l15) * HID + kb];
        #pragma unroll
        for (int rt = 0; rt < 4; ++rt) {
            int gr = r0 + rt * 16 + l15;
            short8v a = (gr < ntot) ? *(const short8v*)&A[(size_t)gr * HID + kb] : zero8();
            acc[rt][0] = __builtin_amdgcn_mfma_f32_16x16x32_bf16(a, b0, acc[rt][0], 0, 0, 0);
            acc[rt][1] = __builtin_amdgcn_mfma_f32_16x16x32_bf16(a, b1, acc[rt][1], 0, 0, 0);
        }
    }
    #pragma unroll
    for (int rt = 0; rt < 4; ++rt)
        #pragma unroll
        for (int i = 0; i < 4; ++i) {
            int gr = r0 + rt * 16 + lg * 4 + i;
            if (gr < ntot) {
                C[(size_t)gr * HID + cbase + l15]      = f2bf1(acc[rt][0][i]);
                C[(size_t)gr * HID + cbase + 16 + l15] = f2bf1(acc[rt][1][i]);
            }
        }
}

// ---------------- mean pool (bf16 input): 64 rows/block ----------------
__global__ void k_pool(const unsigned short* __restrict__ x, const int* __restrict__ batch,
                       float* __restrict__ pool, int* __restrict__ cnt, int n) {
    const int ROWS = 64;
    int start = blockIdx.x * ROWS;
    if (start >= n) return;
    int end = start + ROWS; if (end > n) end = n;
    int c = threadIdx.x;
    float acc = 0.f;
    int cur = batch[start];
    int run = 0;
    for (int r = start; r < end; ++r) {
        int b = batch[r];
        if (b != cur) {
            atomicAdd(&pool[cur * HID + c], acc);
            if (c == 0) atomicAdd(&cnt[cur], run);
            acc = 0.f; run = 0; cur = b;
        }
        acc += bf2f(x[(size_t)r * HID + c]);
        run++;
    }
    atomicAdd(&pool[cur * HID + c], acc);
    if (c == 0) atomicAdd(&cnt[cur], run);
}

// ---------------- pool-div + timestep emb + combo table ----------------
__global__ void k_combo2(const int* __restrict__ t, const float* __restrict__ Wt1,
                         const float* __restrict__ bt1, const float* __restrict__ Wt2,
                         const float* __restrict__ bt2,
                         const float* __restrict__ pool, const int* __restrict__ cntb,
                         const float* __restrict__ Wn1, const float* __restrict__ bn1,
                         float* __restrict__ combo) {
    __shared__ float th[HID];
    __shared__ float pe[HID];
    __shared__ float te[HID];
    int b = blockIdx.x, c = threadIdx.x;
    float tv = (float)t[b];
    float hv = tv * Wt1[c] + bt1[c];
    th[c] = hv > 0.f ? hv : 0.f;
    float dcnt = (float)cntb[b]; if (dcnt < 1.f) dcnt = 1.f;
    pe[c] = pool[b * HID + c] / dcnt;
    __syncthreads();
    float s = bt2[c];
    for (int k = 0; k < HID; ++k) s += th[k] * Wt2[k * HID + c];
    te[c] = s;
    __syncthreads();
    const float* Wp = Wn1 + 128 * HID;
    const float* Wt = Wn1 + 256 * HID;
    float o = bn1[c];
    for (int k = 0; k < HID; ++k)
        o += pe[k] * Wp[k * HID + c] + te[k] * Wt[k * HID + c];
    combo[b * HID + c] = o;
}

// ---------------- fused final head (MFMA main GEMM + epilogue + 128x3) ----------------
__global__ __launch_bounds__(256) void k_final(const unsigned short* __restrict__ A,
        const unsigned short* __restrict__ Bt /* Wn1t[0:128] */,
        const float* __restrict__ Wn1, const float* __restrict__ combo,
        const int* __restrict__ mbatch, const float* __restrict__ noisy,
        const float* __restrict__ Wn2, const float* __restrict__ bn2,
        float* __restrict__ out, int n) {
    __shared__ float hsm[64][132];
    const int tid = threadIdx.x;
    const int wid = tid >> 6;
    const int lane = tid & 63;
    const int l15 = lane & 15, lg = lane >> 4;
    const int r0 = blockIdx.x * 64;
    const int cbase = wid * 32;
    f32x4 acc[4][2] = {};
    #pragma unroll
    for (int ks = 0; ks < 4; ++ks) {
        int kb = ks * 32 + lg * 8;
        short8v b0 = *(const short8v*)&Bt[(size_t)(cbase + l15) * HID + kb];
        short8v b1 = *(const short8v*)&Bt[(size_t)(cbase + 16 + l15) * HID + kb];
        #pragma unroll
        for (int rt = 0; rt < 4; ++rt) {
            int gr = r0 + rt * 16 + l15;
            short8v a = (gr < n) ? *(const short8v*)&A[(size_t)gr * HID + kb] : zero8();
            acc[rt][0] = __builtin_amdgcn_mfma_f32_16x16x32_bf16(a, b0, acc[rt][0], 0, 0, 0);
            acc[rt][1] = __builtin_amdgcn_mfma_f32_16x16x32_bf16(a, b1, acc[rt][1], 0, 0, 0);
        }
    }
    const float* Wna = Wn1 + 384 * HID;
    #pragma unroll
    for (int rt = 0; rt < 4; ++rt)
        #pragma unroll
        for (int i = 0; i < 4; ++i) {
            int lr = rt * 16 + lg * 4 + i;
            int gr = r0 + lr;
            if (gr < n) {
                int b = mbatch[gr];
                float na0 = noisy[gr * 3 + 0], na1 = noisy[gr * 3 + 1], na2 = noisy[gr * 3 + 2];
                #pragma unroll
                for (int ct = 0; ct < 2; ++ct) {
                    int col = cbase + ct * 16 + l15;
                    float v = acc[rt][ct][i]
                            + na0 * Wna[col] + na1 * Wna[HID + col] + na2 * Wna[2 * HID + col]
                            + combo[b * HID + col];
                    hsm[lr][col] = v > 0.f ? v : 0.f;
                }
            }
        }
    __syncthreads();
    if (tid < 192) {
        int lr = tid / 3, j = tid - lr * 3;
        int gr = r0 + lr;
        if (gr < n) {
            float s = bn2[j];
            for (int c = 0; c < HID; ++c) s += hsm[lr][c] * Wn2[c * 3 + j];
            out[(size_t)gr * 3 + j] = s;
        }
    }
}

// ---------------- host ----------------
extern "C" void kernel_launch(void* const* d_in, const int* in_sizes, int n_in,
                              void* d_out, int out_size, void* d_ws, size_t ws_size,
                              hipStream_t stream) {
    const int*   p_res  = (const int*)d_in[0];
    const float* p_pos  = (const float*)d_in[1];
    const int*   p_ei   = (const int*)d_in[2];
    const int*   p_bat  = (const int*)d_in[3];
    const int*   m_res  = (const int*)d_in[4];
    const float* m_pos  = (const float*)d_in[5];
    const int*   m_ei   = (const int*)d_in[6];
    const int*   m_bat  = (const int*)d_in[7];
    const int*   t      = (const int*)d_in[8];
    const float* noisy  = (const float*)d_in[9];
    const float* Wp1 = (const float*)d_in[10], *bp1 = (const float*)d_in[11];
    const float* Wp2 = (const float*)d_in[12], *bp2 = (const float*)d_in[13];
    const float* Wm1 = (const float*)d_in[14], *bm1 = (const float*)d_in[15];
    const float* Wm2 = (const float*)d_in[16], *bm2 = (const float*)d_in[17];
    const float* Wt1 = (const float*)d_in[18], *bt1 = (const float*)d_in[19];
    const float* Wt2 = (const float*)d_in[20], *bt2 = (const float*)d_in[21];
    const float* Wn1 = (const float*)d_in[22], *bn1 = (const float*)d_in[23];
    const float* Wn2 = (const float*)d_in[24], *bn2 = (const float*)d_in[25];
    float* out = (float*)d_out;

    const int NP = in_sizes[0];
    const int EP = in_sizes[2] / 2;
    const int NM = in_sizes[4];
    const int EM = in_sizes[6] / 2;
    const int B  = in_sizes[8];
    auto al64 = [](int x) { return (x + 63) & ~63; };

    const int np64 = al64(NP);
    const long ntot_m = (long)np64 + NM;
    const long e2sum = (long)EP + EM;

    auto align256 = [](size_t x) { return (x + 255) & ~(size_t)255; };
    size_t req = 0;
    auto count = [&](size_t nb) { req = align256(req) + nb; };
    count(4ull * ntot_m);            // deg
    count(4ull * (ntot_m + 1));      // offs
    count(4ull * ntot_m);            // dinv
    count(4ull * 1026);              // bcur
    count(8ull * e2sum);             // csre
    count(2ull * ntot_m * HID);      // hb bf16
    count(2ull * ntot_m * HID);      // hc bf16
    count(2ull * 3 * HID * HID);     // w2ta, w2tb, wn1t
    count(4ull * (size_t)B * (HID + 1)); // pool + cntb
    count(4ull * (size_t)B * HID);   // combo
    count(4ull * 512);               // part
    bool merged = ws_size >= req + 4096;

    char* ws = (char*)d_ws;
    size_t off = 0;
    auto alloc = [&](size_t nb) { off = align256(off); size_t r = off; off += nb; return r; };

    const int NMAX = NP > NM ? NP : NM;
    const int EMAXs = EP > EM ? EP : EM;
    const long ntot_a = merged ? ntot_m : (long)al64(NMAX);
    const long etot_a = merged ? e2sum : (long)EMAXs;

    int*   deg  = (int*)(ws + alloc(4ull * ntot_a));
    int*   offs = (int*)(ws + alloc(4ull * (ntot_a + 1)));
    float* dinv = (float*)(ws + alloc(4ull * ntot_a));
    int*   bcur = (int*)(ws + alloc(4ull * 1026));
    int2*  csre = (int2*)(ws + alloc(8ull * etot_a));
    unsigned short* hb = (unsigned short*)(ws + alloc(2ull * ntot_a * HID));
    unsigned short* hc = (unsigned short*)(ws + alloc(2ull * ntot_a * HID));
    unsigned short* w2ta = (unsigned short*)(ws + alloc(2ull * 3 * HID * HID));
    unsigned short* w2tb = w2ta + HID * HID;
    unsigned short* wn1t = w2ta + 2 * HID * HID;
    float* pool = (float*)(ws + alloc(4ull * (size_t)B * (HID + 1)));
    int*   cntb = (int*)(pool + (size_t)B * HID);
    float* combo = (float*)(ws + alloc(4ull * (size_t)B * HID));
    int*   part = (int*)(ws + alloc(4ull * 512));

    // transpose weights once (covers both merged and fallback paths)
    k_tr<<<384, HID, 0, stream>>>(Wp2, Wm2, Wn1, w2ta, w2tb, wn1t);

    auto run = [&](int np_, int nm_,
                   const int* ei1, int e1, const int* ei2, int e2,
                   const int* res1, const float* pos1, const int* res2, const float* pos2,
                   const float* W1a, const float* b1a, const float* W1b, const float* b1b,
                   const float* b2a, const float* b2b) {
        const int np64_ = al64(np_);
        const int ntot = np64_ + nm_;
        const long etot = (long)e1 + e2;
        const int nbs = (ntot + 255) / 256;
        const int nb = (ntot + 127) >> BSH;
        const int* s1 = ei1, *d1 = ei1 + e1;
        const int* s2 = ei2, *d2 = ei2 + e2;
        hipMemsetAsync(deg, 0, 4ull * ntot, stream);
        k_degree<<<(int)((etot + 255) / 256), 256, 0, stream>>>(d1, e1, d2, e2, np64_, deg);
        k_scan1<<<nbs, 256, 0, stream>>>(deg, offs, part, ntot);
        k_scan2<<<1, 512, 0, stream>>>(part, nbs);
        k_scan3d<<<nbs, 256, 0, stream>>>(offs, part, deg, dinv, ntot);
        k_binit<<<(nb + 255) / 256, 256, 0, stream>>>(offs, bcur, nb);
        k_part<<<(int)((etot + PCHUNK - 1) / PCHUNK), 256, 0, stream>>>(
            s1, d1, e1, s2, d2, e2, np64_, bcur, csre, nb, etot);
        k_csr<<<nb, 256, 0, stream>>>(csre, offs, dinv, ntot);
        k_layer1<<<(ntot + 7) / 8, 256, 0, stream>>>(res1, pos1, res2, pos2, np_, np64_, nm_,
                                                     W1a, W1b, (ushort4*)hb);
        k_agg<<<(ntot + 7) / 8, 256, 0, stream>>>((const ushort4*)hb, offs, deg, csre, dinv,
                                                  np_, np64_, nm_, b1a, b1b, (ushort4*)hc);
        const int nb1 = np64_ / 64;
        const int nb2 = (nm_ + 63) / 64;
        k_gemm<<<nb1 + nb2, 256, 0, stream>>>(hc, w2ta, w2tb, nb1, np64_, ntot, hb);
        k_agg<<<(ntot + 7) / 8, 256, 0, stream>>>((const ushort4*)hb, offs, deg, csre, dinv,
                                                  np_, np64_, nm_, b2a, b2b, (ushort4*)hc);
    };

    if (merged) {
        run(NP, NM, p_ei, EP, m_ei, EM,
            p_res, p_pos, m_res, m_pos,
            Wp1, bp1, Wm1, bm1, bp2, bm2);
        hipMemsetAsync(pool, 0, 4ull * (size_t)B * (HID + 1), stream);
        k_pool<<<(NP + 63) / 64, HID, 0, stream>>>(hc, p_bat, pool, cntb, NP);
        k_combo2<<<B, HID, 0, stream>>>(t, Wt1, bt1, Wt2, bt2, pool, cntb, Wn1, bn1, combo);
        k_final<<<(NM + 63) / 64, 256, 0, stream>>>(hc + (size_t)np64 * HID, wn1t, Wn1, combo,
                                                    m_bat, noisy, Wn2, bn2, out, NM);
    } else {
        run(NP, 0, p_ei, EP, p_ei, 0,
            p_res, p_pos, p_res, p_pos,
            Wp1, bp1, Wp1, bp1, bp2, bp2);
        hipMemsetAsync(pool, 0, 4ull * (size_t)B * (HID + 1), stream);
        k_pool<<<(NP + 63) / 64, HID, 0, stream>>>(hc, p_bat, pool, cntb, NP);
        k_combo2<<<B, HID, 0, stream>>>(t, Wt1, bt1, Wt2, bt2, pool, cntb, Wn1, bn1, combo);
        run(0, NM, m_ei, 0, m_ei, EM,
            m_res, m_pos, m_res, m_pos,
            Wm1, bm1, Wm1, bm1, bm2, bm2);
        k_final<<<(NM + 63) / 64, 256, 0, stream>>>(hc, wn1t, Wn1, combo, m_bat, noisy,
                                                    Wn2, bn2, out, NM);
    }
}

// Round 6
// 283.407 us; speedup vs baseline: 3.0386x; 1.2605x over previous
//
#include <hip/hip_runtime.h>
#include <hip/hip_bf16.h>

#define HID 128
#define BSH 7            // bucket = 128 consecutive dst nodes
#define CSRCAP 4096      // per-bucket edge capacity for LDS sort (mean ~2050, 45 sigma)
#define PCHUNK 4096      // edges per partition block
#define HCHUNK 16384     // edges per bucket-hist block

typedef __attribute__((ext_vector_type(8))) short short8v;
typedef __attribute__((ext_vector_type(4))) float f32x4;

__device__ __forceinline__ float4 f4fma(float a, float4 x, float4 y) {
    y.x += a * x.x; y.y += a * x.y; y.z += a * x.z; y.w += a * x.w; return y;
}
__device__ __forceinline__ unsigned f2bf2(float lo, float hi) {
    unsigned ul = __float_as_uint(lo), uh = __float_as_uint(hi);
    ul = (ul + 0x7FFF + ((ul >> 16) & 1)) >> 16;
    uh = (uh + 0x7FFF + ((uh >> 16) & 1)) & 0xFFFF0000u;
    return ul | uh;
}
__device__ __forceinline__ unsigned short f2bf1(float v) {
    unsigned u = __float_as_uint(v);
    u = (u + 0x7FFF + ((u >> 16) & 1)) >> 16;
    return (unsigned short)u;
}
__device__ __forceinline__ float bf2f(unsigned short b) {
    return __uint_as_float(((unsigned)b) << 16);
}
__device__ __forceinline__ float bflo(unsigned u) { return __uint_as_float(u << 16); }
__device__ __forceinline__ float bfhi(unsigned u) { return __uint_as_float(u & 0xFFFF0000u); }
__device__ __forceinline__ short8v zero8() {
    short8v z = {0, 0, 0, 0, 0, 0, 0, 0};
    return z;
}

// ---------------- bucket histogram ----------------
__global__ __launch_bounds__(256) void k_bhist(const int* __restrict__ d1, int e1,
        const int* __restrict__ d2, int e2, int base2,
        int* __restrict__ bktcnt, long etot) {
    __shared__ int hist[1024];
    int tid = threadIdx.x;
    for (int b = tid; b < 1024; b += 256) hist[b] = 0;
    __syncthreads();
    long start = (long)blockIdx.x * HCHUNK;
    long end = start + HCHUNK; if (end > etot) end = etot;
    for (long i = start + tid; i < end; i += 256) {
        int d = (i < e1) ? d1[i] : d2[i - e1] + base2;
        atomicAdd(&hist[d >> BSH], 1);
    }
    __syncthreads();
    for (int b = tid; b < 1024; b += 256)
        if (hist[b]) atomicAdd(&bktcnt[b], hist[b]);
}

// ---------------- bucket scan (1024 entries, one block) ----------------
__global__ void k_bscan(const int* __restrict__ bktcnt, int* __restrict__ bofs,
                        int* __restrict__ bcur) {
    __shared__ int s[1024];
    int tid = threadIdx.x;
    int v = bktcnt[tid];
    s[tid] = v; __syncthreads();
    for (int o = 1; o < 1024; o <<= 1) {
        int t = (tid >= o) ? s[tid - o] : 0;
        __syncthreads();
        s[tid] += t;
        __syncthreads();
    }
    int ex = s[tid] - v;
    bofs[tid] = ex;
    bcur[tid] = ex;
    if (tid == 1023) bofs[1024] = s[1023];
}

// ---------------- partition edges into bucket-grouped order ----------------
__global__ __launch_bounds__(256) void k_part(
        const int* __restrict__ s1, const int* __restrict__ d1, int e1,
        const int* __restrict__ s2, const int* __restrict__ d2, int e2, int base2,
        int* __restrict__ bcur, int2* __restrict__ pedge, int nb, long etot) {
    __shared__ int hist[1024];
    __shared__ int lofs[1024];
    __shared__ int gb[1024];
    __shared__ int ps[256];
    __shared__ int2 stage[PCHUNK];
    __shared__ unsigned short sbk[PCHUNK];
    int tid = threadIdx.x;
    long cbase = (long)blockIdx.x * PCHUNK;
    int cnt = (int)((etot - cbase) < PCHUNK ? (etot - cbase) : PCHUNK);
    for (int b = tid; b < 1024; b += 256) hist[b] = 0;
    __syncthreads();
    for (int i = tid; i < cnt; i += 256) {
        long e = cbase + i;
        int d = (e < e1) ? d1[e] : d2[e - e1] + base2;
        atomicAdd(&hist[d >> BSH], 1);
    }
    __syncthreads();
    int h0 = hist[tid * 4], h1 = hist[tid * 4 + 1], h2 = hist[tid * 4 + 2], h3 = hist[tid * 4 + 3];
    int sum = h0 + h1 + h2 + h3;
    ps[tid] = sum; __syncthreads();
    for (int o = 1; o < 256; o <<= 1) {
        int v = (tid >= o) ? ps[tid - o] : 0;
        __syncthreads();
        ps[tid] += v;
        __syncthreads();
    }
    int ex = ps[tid] - sum;
    lofs[tid * 4] = ex; lofs[tid * 4 + 1] = ex + h0;
    lofs[tid * 4 + 2] = ex + h0 + h1; lofs[tid * 4 + 3] = ex + h0 + h1 + h2;
    __syncthreads();
    for (int b = tid; b < nb; b += 256) {
        int c = hist[b];
        gb[b] = c ? atomicAdd(&bcur[b], c) : 0;
    }
    __syncthreads();
    for (int b = tid; b < 1024; b += 256) hist[b] = 0;
    __syncthreads();
    for (int i = tid; i < cnt; i += 256) {
        long e = cbase + i;
        int s, d;
        if (e < e1) { s = s1[e]; d = d1[e]; }
        else { s = s2[e - e1] + base2; d = d2[e - e1] + base2; }
        int b = d >> BSH;
        int p = lofs[b] + atomicAdd(&hist[b], 1);
        stage[p] = make_int2(s, d);
        sbk[p] = (unsigned short)b;
    }
    __syncthreads();
    for (int i = tid; i < cnt; i += 256) {
        int b = sbk[i];
        pedge[gb[b] + (i - lofs[b])] = stage[i];
    }
}

// ---------------- per-bucket counting sort -> src-only CSR + deg/offs/dinv ----------------
__global__ __launch_bounds__(256) void k_csr(const int2* __restrict__ pe,
        const int* __restrict__ bofs, int* __restrict__ csrs,
        int* __restrict__ deg, int* __restrict__ offs, float* __restrict__ dinv, int n) {
    __shared__ int lcnt[128];
    __shared__ int lofs2[128];
    __shared__ int lcur[128];
    __shared__ int sc[128];
    __shared__ int ss[CSRCAP];
    int b = blockIdx.x, tid = threadIdx.x;
    int n0 = b << BSH;
    int nn = (n - n0) < 128 ? (n - n0) : 128;
    if (tid < 128) { lcnt[tid] = 0; lcur[tid] = 0; }
    __syncthreads();
    int base = bofs[b], total = bofs[b + 1] - base;
    for (int i = tid; i < total; i += 256) atomicAdd(&lcnt[pe[base + i].y - n0], 1);
    __syncthreads();
    int v = 0;
    if (tid < 128) { v = lcnt[tid]; sc[tid] = v; }
    __syncthreads();
    for (int o = 1; o < 128; o <<= 1) {
        int t = 0;
        if (tid < 128 && tid >= o) t = sc[tid - o];
        __syncthreads();
        if (tid < 128) sc[tid] += t;
        __syncthreads();
    }
    if (tid < 128) lofs2[tid] = sc[tid] - v;
    if (tid < nn) {
        offs[n0 + tid] = base + sc[tid] - v;
        deg[n0 + tid] = v;
        dinv[n0 + tid] = rsqrtf((float)(v + 1)); // +1 self loop
    }
    __syncthreads();
    if (total <= CSRCAP) {
        for (int i = tid; i < total; i += 256) {
            int2 e = pe[base + i];
            int ln = e.y - n0;
            int pos = lofs2[ln] + atomicAdd(&lcur[ln], 1);
            ss[pos] = e.x;
        }
        __syncthreads();
        for (int i = tid; i < total; i += 256) csrs[base + i] = ss[i];
    } else { // safety net (uncoalesced but correct)
        for (int i = tid; i < total; i += 256) {
            int2 e = pe[base + i];
            int ln = e.y - n0;
            int pos = lofs2[ln] + atomicAdd(&lcur[ln], 1);
            csrs[base + pos] = e.x;
        }
    }
}

// ---------------- layer-1 msg, pre-scaled by dinv[g], bf16 ----------------
__global__ __launch_bounds__(256) void k_layer1(
        const int* __restrict__ res1, const float* __restrict__ pos1,
        const int* __restrict__ res2, const float* __restrict__ pos2,
        int np, int np64, int nm, const float* __restrict__ dinv,
        const float* __restrict__ W1a, const float* __restrict__ W1b,
        uint2* __restrict__ hb) {
    int g = blockIdx.x * 8 + (threadIdx.x >> 5);
    int lane = threadIdx.x & 31;
    const int* res; const float* pos; const float4* W4; int base;
    if (g < np) { res = res1; pos = pos1; W4 = (const float4*)W1a; base = 0; }
    else if (g < np64) return;
    else if (g < np64 + nm) { res = res2; pos = pos2; W4 = (const float4*)W1b; base = np64; }
    else return;
    int lg = g - base;
    float4 u = W4[res[lg] * 32 + lane];
    u = f4fma(pos[lg * 3 + 0], W4[20 * 32 + lane], u);
    u = f4fma(pos[lg * 3 + 1], W4[21 * 32 + lane], u);
    u = f4fma(pos[lg * 3 + 2], W4[22 * 32 + lane], u);
    float di = dinv[g];
    uint2 o;
    o.x = f2bf2(di * u.x, di * u.y);
    o.y = f2bf2(di * u.z, di * u.w);
    hb[(size_t)g * 32 + lane] = o;
}

// ---------------- pull aggregation: src-only CSR, 2 edges per instruction ----------------
// hb rows are pre-scaled by dinv[src]; out = relu(dinv[g]*(self + sum) + bias), bf16.
__global__ __launch_bounds__(256) void k_agg(
        const unsigned* __restrict__ hb, const int* __restrict__ offs,
        const int* __restrict__ deg, const int* __restrict__ csrs,
        const float* __restrict__ dinv,
        int np, int np64, int nm,
        const float* __restrict__ ba, const float* __restrict__ bb_,
        unsigned short* __restrict__ outb) {
    int g = blockIdx.x * 8 + (threadIdx.x >> 5);
    const float4* bp;
    if (g < np) bp = (const float4*)ba;
    else if (g < np64) return;
    else if (g < np64 + nm) bp = (const float4*)bb_;
    else return;
    int lane = threadIdx.x & 31;
    int half = lane >> 4, l15 = lane & 15;
    const uint4* H = (const uint4*)hb;   // 16 uint4 per 128-ch row
    float acc[8];
    if (half == 0) {
        uint4 u = H[(size_t)g * 16 + l15];
        acc[0] = bflo(u.x); acc[1] = bfhi(u.x);
        acc[2] = bflo(u.y); acc[3] = bfhi(u.y);
        acc[4] = bflo(u.z); acc[5] = bfhi(u.z);
        acc[6] = bflo(u.w); acc[7] = bfhi(u.w);
    } else {
        #pragma unroll
        for (int c = 0; c < 8; ++c) acc[c] = 0.f;
    }
    int s0 = offs[g], m = deg[g];
    for (int c0 = 0; c0 < m; c0 += 32) {
        int rem = m - c0; if (rem > 32) rem = 32;
        int li = lane < rem ? lane : rem - 1;
        int se = csrs[s0 + c0 + li];           // one coalesced 128B load per 32 edges
        int npair = (rem + 1) >> 1;
        #pragma unroll 4
        for (int j = 0; j < npair; ++j) {
            int idx = 2 * j + half;
            bool act = idx < rem;
            int s = __shfl(se, act ? idx : 0, 32);
            uint4 u = H[(size_t)s * 16 + l15];
            if (act) {
                acc[0] += bflo(u.x); acc[1] += bfhi(u.x);
                acc[2] += bflo(u.y); acc[3] += bfhi(u.y);
                acc[4] += bflo(u.z); acc[5] += bfhi(u.z);
                acc[6] += bflo(u.w); acc[7] += bfhi(u.w);
            }
        }
    }
    #pragma unroll
    for (int c = 0; c < 8; ++c) acc[c] += __shfl_xor(acc[c], 16, 32);
    if (half == 0) {
        float di = dinv[g];
        float4 b0 = bp[l15 * 2], b1 = bp[l15 * 2 + 1];
        float o0 = fmaxf(di * acc[0] + b0.x, 0.f), o1 = fmaxf(di * acc[1] + b0.y, 0.f);
        float o2 = fmaxf(di * acc[2] + b0.z, 0.f), o3 = fmaxf(di * acc[3] + b0.w, 0.f);
        float o4 = fmaxf(di * acc[4] + b1.x, 0.f), o5 = fmaxf(di * acc[5] + b1.y, 0.f);
        float o6 = fmaxf(di * acc[6] + b1.z, 0.f), o7 = fmaxf(di * acc[7] + b1.w, 0.f);
        uint4 pk;
        pk.x = f2bf2(o0, o1); pk.y = f2bf2(o2, o3);
        pk.z = f2bf2(o4, o5); pk.w = f2bf2(o6, o7);
        *(uint4*)&outb[(size_t)g * HID + l15 * 8] = pk;
    }
}

// ---------------- weight transpose fp32 -> bf16 [col][k] ----------------
__global__ void k_tr(const float* __restrict__ Wa, const float* __restrict__ Wb,
                     const float* __restrict__ Wc,
                     unsigned short* __restrict__ Ta, unsigned short* __restrict__ Tb,
                     unsigned short* __restrict__ Tc) {
    int b = blockIdx.x;                // 0..383
    int col = b & 127, m = b >> 7;
    const float* W = (m == 0) ? Wa : (m == 1 ? Wb : Wc);
    unsigned short* T = (m == 0) ? Ta : (m == 1 ? Tb : Tc);
    int k = threadIdx.x;
    T[col * HID + k] = f2bf1(W[k * HID + col]);
}

// ---------------- MFMA bf16 GEMM: C[r](bf16) = dinv[r] * (A[r] @ W) ----------------
__global__ __launch_bounds__(256) void k_gemm(const unsigned short* __restrict__ A,
        const unsigned short* __restrict__ Bt1, const unsigned short* __restrict__ Bt2,
        int nb1, int np64, int ntot, const float* __restrict__ dinv,
        unsigned short* __restrict__ C) {
    const int tid = threadIdx.x;
    const int wid = tid >> 6;
    const int lane = tid & 63;
    const int l15 = lane & 15, lg = lane >> 4;
    const unsigned short* Bt; int r0;
    if ((int)blockIdx.x < nb1) { Bt = Bt1; r0 = blockIdx.x * 64; }
    else { Bt = Bt2; r0 = np64 + ((int)blockIdx.x - nb1) * 64; }
    const int cbase = wid * 32;
    f32x4 acc[4][2] = {};
    #pragma unroll
    for (int ks = 0; ks < 4; ++ks) {
        int kb = ks * 32 + lg * 8;
        short8v b0 = *(const short8v*)&Bt[(size_t)(cbase + l15) * HID + kb];
        short8v b1 = *(const short8v*)&Bt[(size_t)(cbase + 16 + l15) * HID + kb];
        #pragma unroll
        for (int rt = 0; rt < 4; ++rt) {
            int gr = r0 + rt * 16 + l15;
            short8v a = (gr < ntot) ? *(const short8v*)&A[(size_t)gr * HID + kb] : zero8();
            acc[rt][0] = __builtin_amdgcn_mfma_f32_16x16x32_bf16(a, b0, acc[rt][0], 0, 0, 0);
            acc[rt][1] = __builtin_amdgcn_mfma_f32_16x16x32_bf16(a, b1, acc[rt][1], 0, 0, 0);
        }
    }
    #pragma unroll
    for (int rt = 0; rt < 4; ++rt)
        #pragma unroll
        for (int i = 0; i < 4; ++i) {
            int gr = r0 + rt * 16 + lg * 4 + i;
            if (gr < ntot) {
                float di = dinv[gr];
                C[(size_t)gr * HID + cbase + l15]      = f2bf1(di * acc[rt][0][i]);
                C[(size_t)gr * HID + cbase + 16 + l15] = f2bf1(di * acc[rt][1][i]);
            }
        }
}

// ---------------- mean pool (bf16 input): 64 rows/block ----------------
__global__ void k_pool(const unsigned short* __restrict__ x, const int* __restrict__ batch,
                       float* __restrict__ pool, int* __restrict__ cnt, int n) {
    const int ROWS = 64;
    int start = blockIdx.x * ROWS;
    if (start >= n) return;
    int end = start + ROWS; if (end > n) end = n;
    int c = threadIdx.x;
    float acc = 0.f;
    int cur = batch[start];
    int run = 0;
    for (int r = start; r < end; ++r) {
        int b = batch[r];
        if (b != cur) {
            atomicAdd(&pool[cur * HID + c], acc);
            if (c == 0) atomicAdd(&cnt[cur], run);
            acc = 0.f; run = 0; cur = b;
        }
        acc += bf2f(x[(size_t)r * HID + c]);
        run++;
    }
    atomicAdd(&pool[cur * HID + c], acc);
    if (c == 0) atomicAdd(&cnt[cur], run);
}

// ---------------- pool-div + timestep emb + combo table ----------------
__global__ void k_combo2(const int* __restrict__ t, const float* __restrict__ Wt1,
                         const float* __restrict__ bt1, const float* __restrict__ Wt2,
                         const float* __restrict__ bt2,
                         const float* __restrict__ pool, const int* __restrict__ cntb,
                         const float* __restrict__ Wn1, const float* __restrict__ bn1,
                         float* __restrict__ combo) {
    __shared__ float th[HID];
    __shared__ float pe[HID];
    __shared__ float te[HID];
    int b = blockIdx.x, c = threadIdx.x;
    float tv = (float)t[b];
    float hv = tv * Wt1[c] + bt1[c];
    th[c] = hv > 0.f ? hv : 0.f;
    float dcnt = (float)cntb[b]; if (dcnt < 1.f) dcnt = 1.f;
    pe[c] = pool[b * HID + c] / dcnt;
    __syncthreads();
    float s = bt2[c];
    for (int k = 0; k < HID; ++k) s += th[k] * Wt2[k * HID + c];
    te[c] = s;
    __syncthreads();
    const float* Wp = Wn1 + 128 * HID;
    const float* Wt = Wn1 + 256 * HID;
    float o = bn1[c];
    for (int k = 0; k < HID; ++k)
        o += pe[k] * Wp[k * HID + c] + te[k] * Wt[k * HID + c];
    combo[b * HID + c] = o;
}

// ---------------- fused final head (MFMA GEMM + epilogue + 128x3) ----------------
__global__ __launch_bounds__(256) void k_final(const unsigned short* __restrict__ A,
        const unsigned short* __restrict__ Bt /* Wn1t[0:128] */,
        const float* __restrict__ Wn1, const float* __restrict__ combo,
        const int* __restrict__ mbatch, const float* __restrict__ noisy,
        const float* __restrict__ Wn2, const float* __restrict__ bn2,
        float* __restrict__ out, int n) {
    __shared__ float hsm[64][132];
    const int tid = threadIdx.x;
    const int wid = tid >> 6;
    const int lane = tid & 63;
    const int l15 = lane & 15, lg = lane >> 4;
    const int r0 = blockIdx.x * 64;
    const int cbase = wid * 32;
    f32x4 acc[4][2] = {};
    #pragma unroll
    for (int ks = 0; ks < 4; ++ks) {
        int kb = ks * 32 + lg * 8;
        short8v b0 = *(const short8v*)&Bt[(size_t)(cbase + l15) * HID + kb];
        short8v b1 = *(const short8v*)&Bt[(size_t)(cbase + 16 + l15) * HID + kb];
        #pragma unroll
        for (int rt = 0; rt < 4; ++rt) {
            int gr = r0 + rt * 16 + l15;
            short8v a = (gr < n) ? *(const short8v*)&A[(size_t)gr * HID + kb] : zero8();
            acc[rt][0] = __builtin_amdgcn_mfma_f32_16x16x32_bf16(a, b0, acc[rt][0], 0, 0, 0);
            acc[rt][1] = __builtin_amdgcn_mfma_f32_16x16x32_bf16(a, b1, acc[rt][1], 0, 0, 0);
        }
    }
    const float* Wna = Wn1 + 384 * HID;
    #pragma unroll
    for (int rt = 0; rt < 4; ++rt)
        #pragma unroll
        for (int i = 0; i < 4; ++i) {
            int lr = rt * 16 + lg * 4 + i;
            int gr = r0 + lr;
            if (gr < n) {
                int b = mbatch[gr];
                float na0 = noisy[gr * 3 + 0], na1 = noisy[gr * 3 + 1], na2 = noisy[gr * 3 + 2];
                #pragma unroll
                for (int ct = 0; ct < 2; ++ct) {
                    int col = cbase + ct * 16 + l15;
                    float v = acc[rt][ct][i]
                            + na0 * Wna[col] + na1 * Wna[HID + col] + na2 * Wna[2 * HID + col]
                            + combo[b * HID + col];
                    hsm[lr][col] = v > 0.f ? v : 0.f;
                }
            }
        }
    __syncthreads();
    if (tid < 192) {
        int lr = tid / 3, j = tid - lr * 3;
        int gr = r0 + lr;
        if (gr < n) {
            float s = bn2[j];
            for (int c = 0; c < HID; ++c) s += hsm[lr][c] * Wn2[c * 3 + j];
            out[(size_t)gr * 3 + j] = s;
        }
    }
}

// ---------------- host ----------------
extern "C" void kernel_launch(void* const* d_in, const int* in_sizes, int n_in,
                              void* d_out, int out_size, void* d_ws, size_t ws_size,
                              hipStream_t stream) {
    const int*   p_res  = (const int*)d_in[0];
    const float* p_pos  = (const float*)d_in[1];
    const int*   p_ei   = (const int*)d_in[2];
    const int*   p_bat  = (const int*)d_in[3];
    const int*   m_res  = (const int*)d_in[4];
    const float* m_pos  = (const float*)d_in[5];
    const int*   m_ei   = (const int*)d_in[6];
    const int*   m_bat  = (const int*)d_in[7];
    const int*   t      = (const int*)d_in[8];
    const float* noisy  = (const float*)d_in[9];
    const float* Wp1 = (const float*)d_in[10], *bp1 = (const float*)d_in[11];
    const float* Wp2 = (const float*)d_in[12], *bp2 = (const float*)d_in[13];
    const float* Wm1 = (const float*)d_in[14], *bm1 = (const float*)d_in[15];
    const float* Wm2 = (const float*)d_in[16], *bm2 = (const float*)d_in[17];
    const float* Wt1 = (const float*)d_in[18], *bt1 = (const float*)d_in[19];
    const float* Wt2 = (const float*)d_in[20], *bt2 = (const float*)d_in[21];
    const float* Wn1 = (const float*)d_in[22], *bn1 = (const float*)d_in[23];
    const float* Wn2 = (const float*)d_in[24], *bn2 = (const float*)d_in[25];
    float* out = (float*)d_out;

    const int NP = in_sizes[0];
    const int EP = in_sizes[2] / 2;
    const int NM = in_sizes[4];
    const int EM = in_sizes[6] / 2;
    const int B  = in_sizes[8];
    auto al64 = [](int x) { return (x + 63) & ~63; };

    const int np64 = al64(NP);
    const long ntot_m = (long)np64 + NM;
    const long e2sum = (long)EP + EM;

    auto align256 = [](size_t x) { return (x + 255) & ~(size_t)255; };
    size_t req = 0;
    auto count = [&](size_t nb) { req = align256(req) + nb; };
    count(4ull * ntot_m);            // deg
    count(4ull * ntot_m);            // offs
    count(4ull * ntot_m);            // dinv
    count(4ull * (1024 + 1025 + 1024)); // bktcnt + bofs + bcur
    count(8ull * e2sum);             // csre (int2, bucket-grouped)
    count(4ull * e2sum);             // csrs (src-only)
    count(2ull * ntot_m * HID);      // hb bf16
    count(2ull * ntot_m * HID);      // hc bf16
    count(2ull * 3 * HID * HID);     // w2ta, w2tb, wn1t
    count(4ull * (size_t)B * (HID + 1)); // pool + cntb
    count(4ull * (size_t)B * HID);   // combo
    bool merged = ws_size >= req + 4096;

    char* ws = (char*)d_ws;
    size_t off = 0;
    auto alloc = [&](size_t nb) { off = align256(off); size_t r = off; off += nb; return r; };

    const int NMAX = NP > NM ? NP : NM;
    const int EMAXs = EP > EM ? EP : EM;
    const long ntot_a = merged ? ntot_m : (long)al64(NMAX);
    const long etot_a = merged ? e2sum : (long)EMAXs;

    int*   deg  = (int*)(ws + alloc(4ull * ntot_a));
    int*   offs = (int*)(ws + alloc(4ull * ntot_a));
    float* dinv = (float*)(ws + alloc(4ull * ntot_a));
    int*   bktcnt = (int*)(ws + alloc(4ull * (1024 + 1025 + 1024)));
    int*   bofs = bktcnt + 1024;
    int*   bcur = bofs + 1025;
    int2*  csre = (int2*)(ws + alloc(8ull * etot_a));
    int*   csrs = (int*)(ws + alloc(4ull * etot_a));
    unsigned short* hb = (unsigned short*)(ws + alloc(2ull * ntot_a * HID));
    unsigned short* hc = (unsigned short*)(ws + alloc(2ull * ntot_a * HID));
    unsigned short* w2ta = (unsigned short*)(ws + alloc(2ull * 3 * HID * HID));
    unsigned short* w2tb = w2ta + HID * HID;
    unsigned short* wn1t = w2ta + 2 * HID * HID;
    float* pool = (float*)(ws + alloc(4ull * (size_t)B * (HID + 1)));
    int*   cntb = (int*)(pool + (size_t)B * HID);
    float* combo = (float*)(ws + alloc(4ull * (size_t)B * HID));

    // transpose weights once
    k_tr<<<384, HID, 0, stream>>>(Wp2, Wm2, Wn1, w2ta, w2tb, wn1t);

    auto run = [&](int np_, int nm_,
                   const int* ei1, int e1, const int* ei2, int e2,
                   const int* res1, const float* pos1, const int* res2, const float* pos2,
                   const float* W1a, const float* b1a, const float* W1b, const float* b1b,
                   const float* b2a, const float* b2b) {
        const int np64_ = al64(np_);
        const int ntot = np64_ + nm_;
        const long etot = (long)e1 + e2;
        const int nb = (ntot + 127) >> BSH;
        const int* s1 = ei1, *d1 = ei1 + e1;
        const int* s2 = ei2, *d2 = ei2 + e2;
        hipMemsetAsync(bktcnt, 0, 4096, stream);
        k_bhist<<<(int)((etot + HCHUNK - 1) / HCHUNK), 256, 0, stream>>>(
            d1, e1, d2, e2, np64_, bktcnt, etot);
        k_bscan<<<1, 1024, 0, stream>>>(bktcnt, bofs, bcur);
        k_part<<<(int)((etot + PCHUNK - 1) / PCHUNK), 256, 0, stream>>>(
            s1, d1, e1, s2, d2, e2, np64_, bcur, csre, nb, etot);
        k_csr<<<nb, 256, 0, stream>>>(csre, bofs, csrs, deg, offs, dinv, ntot);
        k_layer1<<<(ntot + 7) / 8, 256, 0, stream>>>(res1, pos1, res2, pos2, np_, np64_, nm_,
                                                     dinv, W1a, W1b, (uint2*)hb);
        k_agg<<<(ntot + 7) / 8, 256, 0, stream>>>((const unsigned*)hb, offs, deg, csrs, dinv,
                                                  np_, np64_, nm_, b1a, b1b, hc);
        const int nb1 = np64_ / 64;
        const int nb2 = (nm_ + 63) / 64;
        k_gemm<<<nb1 + nb2, 256, 0, stream>>>(hc, w2ta, w2tb, nb1, np64_, ntot, dinv, hb);
        k_agg<<<(ntot + 7) / 8, 256, 0, stream>>>((const unsigned*)hb, offs, deg, csrs, dinv,
                                                  np_, np64_, nm_, b2a, b2b, hc);
    };

    if (merged) {
        run(NP, NM, p_ei, EP, m_ei, EM,
            p_res, p_pos, m_res, m_pos,
            Wp1, bp1, Wm1, bm1, bp2, bm2);
        hipMemsetAsync(pool, 0, 4ull * (size_t)B * (HID + 1), stream);
        k_pool<<<(NP + 63) / 64, HID, 0, stream>>>(hc, p_bat, pool, cntb, NP);
        k_combo2<<<B, HID, 0, stream>>>(t, Wt1, bt1, Wt2, bt2, pool, cntb, Wn1, bn1, combo);
        k_final<<<(NM + 63) / 64, 256, 0, stream>>>(hc + (size_t)np64 * HID, wn1t, Wn1, combo,
                                                    m_bat, noisy, Wn2, bn2, out, NM);
    } else {
        run(NP, 0, p_ei, EP, p_ei, 0,
            p_res, p_pos, p_res, p_pos,
            Wp1, bp1, Wp1, bp1, bp2, bp2);
        hipMemsetAsync(pool, 0, 4ull * (size_t)B * (HID + 1), stream);
        k_pool<<<(NP + 63) / 64, HID, 0, stream>>>(hc, p_bat, pool, cntb, NP);
        k_combo2<<<B, HID, 0, stream>>>(t, Wt1, bt1, Wt2, bt2, pool, cntb, Wn1, bn1, combo);
        run(0, NM, m_ei, 0, m_ei, EM,
            m_res, m_pos, m_res, m_pos,
            Wm1, bm1, Wm1, bm1, bm2, bm2);
        k_final<<<(NM + 63) / 64, 256, 0, stream>>>(hc, wn1t, Wn1, combo, m_bat, noisy,
                                                    Wn2, bn2, out, NM);
    }
}

// Round 7
// 261.230 us; speedup vs baseline: 3.2966x; 1.0849x over previous
//
#include <hip/hip_runtime.h>
#include <hip/hip_bf16.h>

#define HID 128
#define BSH 7            // bucket = 128 consecutive dst nodes
#define CSRCAP 4096      // per-bucket edge capacity for LDS sort
#define PCHUNK 4096      // edges per partition block
#define HCHUNK 16384     // edges per bucket-hist block

typedef __attribute__((ext_vector_type(8))) short short8v;
typedef __attribute__((ext_vector_type(4))) float f32x4;

__device__ __forceinline__ float4 f4fma(float a, float4 x, float4 y) {
    y.x += a * x.x; y.y += a * x.y; y.z += a * x.z; y.w += a * x.w; return y;
}
__device__ __forceinline__ unsigned f2bf2(float lo, float hi) {
    unsigned ul = __float_as_uint(lo), uh = __float_as_uint(hi);
    ul = (ul + 0x7FFF + ((ul >> 16) & 1)) >> 16;
    uh = (uh + 0x7FFF + ((uh >> 16) & 1)) & 0xFFFF0000u;
    return ul | uh;
}
__device__ __forceinline__ unsigned short f2bf1(float v) {
    unsigned u = __float_as_uint(v);
    u = (u + 0x7FFF + ((u >> 16) & 1)) >> 16;
    return (unsigned short)u;
}
__device__ __forceinline__ float bflo(unsigned u) { return __uint_as_float(u << 16); }
__device__ __forceinline__ float bfhi(unsigned u) { return __uint_as_float(u & 0xFFFF0000u); }
__device__ __forceinline__ float bf2f(unsigned short b) {
    return __uint_as_float(((unsigned)b) << 16);
}
__device__ __forceinline__ short8v zero8() {
    short8v z = {0, 0, 0, 0, 0, 0, 0, 0};
    return z;
}

// ---------------- bucket histogram ----------------
__global__ __launch_bounds__(256) void k_bhist(const int* __restrict__ d1, int e1,
        const int* __restrict__ d2, int e2, int base2,
        int* __restrict__ bktcnt, long etot) {
    __shared__ int hist[1024];
    int tid = threadIdx.x;
    for (int b = tid; b < 1024; b += 256) hist[b] = 0;
    __syncthreads();
    long start = (long)blockIdx.x * HCHUNK;
    long end = start + HCHUNK; if (end > etot) end = etot;
    for (long i = start + tid; i < end; i += 256) {
        int d = (i < e1) ? d1[i] : d2[i - e1] + base2;
        atomicAdd(&hist[d >> BSH], 1);
    }
    __syncthreads();
    for (int b = tid; b < 1024; b += 256)
        if (hist[b]) atomicAdd(&bktcnt[b], hist[b]);
}

// ---------------- bucket scan ----------------
__global__ void k_bscan(const int* __restrict__ bktcnt, int* __restrict__ bofs,
                        int* __restrict__ bcur) {
    __shared__ int s[1024];
    int tid = threadIdx.x;
    int v = bktcnt[tid];
    s[tid] = v; __syncthreads();
    for (int o = 1; o < 1024; o <<= 1) {
        int t = (tid >= o) ? s[tid - o] : 0;
        __syncthreads();
        s[tid] += t;
        __syncthreads();
    }
    int ex = s[tid] - v;
    bofs[tid] = ex;
    bcur[tid] = ex;
    if (tid == 1023) bofs[1024] = s[1023];
}

// ---------------- partition edges into bucket-grouped order ----------------
__global__ __launch_bounds__(256) void k_part(
        const int* __restrict__ s1, const int* __restrict__ d1, int e1,
        const int* __restrict__ s2, const int* __restrict__ d2, int e2, int base2,
        int* __restrict__ bcur, int2* __restrict__ pedge, int nb, long etot) {
    __shared__ int hist[1024];
    __shared__ int lofs[1024];
    __shared__ int gb[1024];
    __shared__ int ps[256];
    __shared__ int2 stage[PCHUNK];
    __shared__ unsigned short sbk[PCHUNK];
    int tid = threadIdx.x;
    long cbase = (long)blockIdx.x * PCHUNK;
    int cnt = (int)((etot - cbase) < PCHUNK ? (etot - cbase) : PCHUNK);
    for (int b = tid; b < 1024; b += 256) hist[b] = 0;
    __syncthreads();
    for (int i = tid; i < cnt; i += 256) {
        long e = cbase + i;
        int d = (e < e1) ? d1[e] : d2[e - e1] + base2;
        atomicAdd(&hist[d >> BSH], 1);
    }
    __syncthreads();
    int h0 = hist[tid * 4], h1 = hist[tid * 4 + 1], h2 = hist[tid * 4 + 2], h3 = hist[tid * 4 + 3];
    int sum = h0 + h1 + h2 + h3;
    ps[tid] = sum; __syncthreads();
    for (int o = 1; o < 256; o <<= 1) {
        int v = (tid >= o) ? ps[tid - o] : 0;
        __syncthreads();
        ps[tid] += v;
        __syncthreads();
    }
    int ex = ps[tid] - sum;
    lofs[tid * 4] = ex; lofs[tid * 4 + 1] = ex + h0;
    lofs[tid * 4 + 2] = ex + h0 + h1; lofs[tid * 4 + 3] = ex + h0 + h1 + h2;
    __syncthreads();
    for (int b = tid; b < nb; b += 256) {
        int c = hist[b];
        gb[b] = c ? atomicAdd(&bcur[b], c) : 0;
    }
    __syncthreads();
    for (int b = tid; b < 1024; b += 256) hist[b] = 0;
    __syncthreads();
    for (int i = tid; i < cnt; i += 256) {
        long e = cbase + i;
        int s, d;
        if (e < e1) { s = s1[e]; d = d1[e]; }
        else { s = s2[e - e1] + base2; d = d2[e - e1] + base2; }
        int b = d >> BSH;
        int p = lofs[b] + atomicAdd(&hist[b], 1);
        stage[p] = make_int2(s, d);
        sbk[p] = (unsigned short)b;
    }
    __syncthreads();
    for (int i = tid; i < cnt; i += 256) {
        int b = sbk[i];
        pedge[gb[b] + (i - lofs[b])] = stage[i];
    }
}

// ---------------- per-bucket sort -> src CSR + deg/offs/dinv + node records ----------------
__global__ __launch_bounds__(256) void k_csr(const int2* __restrict__ pe,
        const int* __restrict__ bofs, int* __restrict__ csrs,
        int* __restrict__ deg, int* __restrict__ offs, float* __restrict__ dinv,
        const int* __restrict__ res1, const float* __restrict__ pos1,
        const int* __restrict__ res2, const float* __restrict__ pos2,
        int np, int np64, uint4* __restrict__ nrec, int n) {
    __shared__ int lofs2[128];
    __shared__ int lcnt[128];
    __shared__ int lcur[128];
    __shared__ int sc[128];
    __shared__ int ss[CSRCAP];
    int b = blockIdx.x, tid = threadIdx.x;
    int n0 = b << BSH;
    int nn = (n - n0) < 128 ? (n - n0) : 128;
    if (tid < 128) { lcnt[tid] = 0; lcur[tid] = 0; }
    __syncthreads();
    int base = bofs[b], total = bofs[b + 1] - base;
    for (int i = tid; i < total; i += 256) atomicAdd(&lcnt[pe[base + i].y - n0], 1);
    __syncthreads();
    int v = 0;
    if (tid < 128) { v = lcnt[tid]; sc[tid] = v; }
    __syncthreads();
    for (int o = 1; o < 128; o <<= 1) {
        int t = 0;
        if (tid < 128 && tid >= o) t = sc[tid - o];
        __syncthreads();
        if (tid < 128) sc[tid] += t;
        __syncthreads();
    }
    if (tid < 128) lofs2[tid] = sc[tid] - v;
    if (tid < nn) {
        int node = n0 + tid;
        offs[node] = base + sc[tid] - v;
        deg[node] = v;
        float dv = rsqrtf((float)(v + 1)); // +1 self loop
        dinv[node] = dv;
        const int* res = 0; const float* pos = 0; int bseg = 0; bool valid = false;
        if (node < np) { res = res1; pos = pos1; bseg = 0; valid = true; }
        else if (node >= np64) { res = res2; pos = pos2; bseg = np64; valid = true; }
        if (valid) {
            int lg = node - bseg;
            uint4 rr;
            rr.x = __float_as_uint(dv);
            rr.y = (unsigned)res[lg] | ((unsigned)f2bf1(pos[lg * 3 + 0]) << 16);
            rr.z = (unsigned)f2bf1(pos[lg * 3 + 1]) | ((unsigned)f2bf1(pos[lg * 3 + 2]) << 16);
            rr.w = 0;
            nrec[node] = rr;
        }
    }
    __syncthreads();
    if (total <= CSRCAP) {
        for (int i = tid; i < total; i += 256) {
            int2 e = pe[base + i];
            int ln = e.y - n0;
            int pos_ = lofs2[ln] + atomicAdd(&lcur[ln], 1);
            ss[pos_] = e.x;
        }
        __syncthreads();
        for (int i = tid; i < total; i += 256) csrs[base + i] = ss[i];
    } else {
        for (int i = tid; i < total; i += 256) {
            int2 e = pe[base + i];
            int ln = e.y - n0;
            int pos_ = lofs2[ln] + atomicAdd(&lcur[ln], 1);
            csrs[base + pos_] = e.x;
        }
    }
}

// ---------------- layer 1: 23-dim aggregation (L2-resident records) + W1 apply ----------------
// Writes x1s[d] = dinv_d * relu( dinv_d*(sum_s dinv_s*msg_s + dinv_d*msg_d) + b1 ), bf16.
__global__ __launch_bounds__(256) void k_agg23(
        const uint4* __restrict__ nrec, const int* __restrict__ offs,
        const int* __restrict__ deg, const int* __restrict__ csrs,
        int np, int np64, int nm,
        const float* __restrict__ W1a, const float* __restrict__ b1a,
        const float* __restrict__ W1b, const float* __restrict__ b1b,
        uint2* __restrict__ xout) {
    __shared__ float agg[8][20];
    int grp = threadIdx.x >> 5, lane = threadIdx.x & 31;
    int g = blockIdx.x * 8 + grp;
    const float4 *W4, *bp;
    if (g < np) { W4 = (const float4*)W1a; bp = (const float4*)b1a; }
    else if (g >= np64 && g < np64 + nm) { W4 = (const float4*)W1b; bp = (const float4*)b1b; }
    else return;
    if (lane < 20) agg[grp][lane] = 0.f;     // in-wave DS ordering: no barrier needed
    float sx = 0.f, sy = 0.f, sz = 0.f;
    int s0 = offs[g], m = deg[g];
    for (int i = lane; i < m; i += 32) {
        int s = csrs[s0 + i];
        uint4 r = nrec[s];                    // 16B random read, L2-resident (1.6 MB)
        float dv = __uint_as_float(r.x);
        int rs = (int)(r.y & 0xffffu);
        float px = bfhi(r.y);
        float py = bflo(r.z);
        float pz = bfhi(r.z);
        atomicAdd(&agg[grp][rs], dv);
        sx += dv * px; sy += dv * py; sz += dv * pz;
    }
    #pragma unroll
    for (int o = 1; o < 32; o <<= 1) {
        sx += __shfl_xor(sx, o, 32);
        sy += __shfl_xor(sy, o, 32);
        sz += __shfl_xor(sz, o, 32);
    }
    // self record
    uint4 sr = nrec[g];
    float dd = __uint_as_float(sr.x);
    int rsd = (int)(sr.y & 0xffffu);
    float spx = bfhi(sr.y), spy = bflo(sr.z), spz = bfhi(sr.z);
    float4 w20 = W4[20 * 32 + lane], w21 = W4[21 * 32 + lane], w22 = W4[22 * 32 + lane];
    float4 sm = W4[rsd * 32 + lane];
    sm = f4fma(spx, w20, sm); sm = f4fma(spy, w21, sm); sm = f4fma(spz, w22, sm);
    float4 acc = make_float4(dd * sm.x, dd * sm.y, dd * sm.z, dd * sm.w);
    #pragma unroll
    for (int r = 0; r < 20; ++r)
        acc = f4fma(agg[grp][r], W4[r * 32 + lane], acc);
    acc = f4fma(sx, w20, acc);
    acc = f4fma(sy, w21, acc);
    acc = f4fma(sz, w22, acc);
    float4 b = bp[lane];
    float o0 = fmaxf(dd * acc.x + b.x, 0.f);
    float o1 = fmaxf(dd * acc.y + b.y, 0.f);
    float o2 = fmaxf(dd * acc.z + b.z, 0.f);
    float o3 = fmaxf(dd * acc.w + b.w, 0.f);
    uint2 o;
    o.x = f2bf2(dd * o0, dd * o1);
    o.y = f2bf2(dd * o2, dd * o3);
    xout[(size_t)g * 32 + lane] = o;
}

// ---------------- layer 2 pull aggregation (128-dim, pre-scaled rows) ----------------
// a2[d] = dinv_d * (sum_s x1s[s] + x1s[d]), bf16 out (bias/relu deferred to GEMM).
__global__ __launch_bounds__(256) void k_agg(
        const unsigned* __restrict__ hb, const int* __restrict__ offs,
        const int* __restrict__ deg, const int* __restrict__ csrs,
        const float* __restrict__ dinv,
        int np, int np64, int nm,
        unsigned short* __restrict__ outb) {
    int g = blockIdx.x * 8 + (threadIdx.x >> 5);
    if (g >= np && (g < np64 || g >= np64 + nm)) return;
    int lane = threadIdx.x & 31;
    int half = lane >> 4, l15 = lane & 15;
    const uint4* H = (const uint4*)hb;
    float acc[8];
    if (half == 0) {
        uint4 u = H[(size_t)g * 16 + l15];
        acc[0] = bflo(u.x); acc[1] = bfhi(u.x);
        acc[2] = bflo(u.y); acc[3] = bfhi(u.y);
        acc[4] = bflo(u.z); acc[5] = bfhi(u.z);
        acc[6] = bflo(u.w); acc[7] = bfhi(u.w);
    } else {
        #pragma unroll
        for (int c = 0; c < 8; ++c) acc[c] = 0.f;
    }
    int s0 = offs[g], m = deg[g];
    for (int c0 = 0; c0 < m; c0 += 32) {
        int rem = m - c0; if (rem > 32) rem = 32;
        int li = lane < rem ? lane : rem - 1;
        int se = csrs[s0 + c0 + li];
        int npair = (rem + 1) >> 1;
        #pragma unroll 8
        for (int j = 0; j < npair; ++j) {
            int idx = 2 * j + half;
            bool act = idx < rem;
            int s = __shfl(se, act ? idx : 0, 32);
            uint4 u = H[(size_t)s * 16 + l15];
            if (act) {
                acc[0] += bflo(u.x); acc[1] += bfhi(u.x);
                acc[2] += bflo(u.y); acc[3] += bfhi(u.y);
                acc[4] += bflo(u.z); acc[5] += bfhi(u.z);
                acc[6] += bflo(u.w); acc[7] += bfhi(u.w);
            }
        }
    }
    #pragma unroll
    for (int c = 0; c < 8; ++c) acc[c] += __shfl_xor(acc[c], 16, 32);
    if (half == 0) {
        float di = dinv[g];
        uint4 pk;
        pk.x = f2bf2(di * acc[0], di * acc[1]);
        pk.y = f2bf2(di * acc[2], di * acc[3]);
        pk.z = f2bf2(di * acc[4], di * acc[5]);
        pk.w = f2bf2(di * acc[6], di * acc[7]);
        *(uint4*)&outb[(size_t)g * HID + l15 * 8] = pk;
    }
}

// ---------------- weight transpose fp32 -> bf16 [col][k] ----------------
__global__ void k_tr(const float* __restrict__ Wa, const float* __restrict__ Wb,
                     const float* __restrict__ Wc,
                     unsigned short* __restrict__ Ta, unsigned short* __restrict__ Tb,
                     unsigned short* __restrict__ Tc) {
    int b = blockIdx.x;
    int col = b & 127, m = b >> 7;
    const float* W = (m == 0) ? Wa : (m == 1 ? Wb : Wc);
    unsigned short* T = (m == 0) ? Ta : (m == 1 ? Tb : Tc);
    int k = threadIdx.x;
    T[col * HID + k] = f2bf1(W[k * HID + col]);
}

// ---------------- MFMA bf16 GEMM: C = relu(A @ W + b), bf16 out ----------------
__global__ __launch_bounds__(256) void k_gemm(const unsigned short* __restrict__ A,
        const unsigned short* __restrict__ Bt1, const unsigned short* __restrict__ Bt2,
        const float* __restrict__ b2a, const float* __restrict__ b2b,
        int nb1, int np64, int ntot, unsigned short* __restrict__ C) {
    const int tid = threadIdx.x;
    const int wid = tid >> 6;
    const int lane = tid & 63;
    const int l15 = lane & 15, lg = lane >> 4;
    const unsigned short* Bt; const float* bb; int r0;
    if ((int)blockIdx.x < nb1) { Bt = Bt1; bb = b2a; r0 = blockIdx.x * 64; }
    else { Bt = Bt2; bb = b2b; r0 = np64 + ((int)blockIdx.x - nb1) * 64; }
    const int cbase = wid * 32;
    f32x4 acc[4][2] = {};
    #pragma unroll
    for (int ks = 0; ks < 4; ++ks) {
        int kb = ks * 32 + lg * 8;
        short8v b0 = *(const short8v*)&Bt[(size_t)(cbase + l15) * HID + kb];
        short8v b1 = *(const short8v*)&Bt[(size_t)(cbase + 16 + l15) * HID + kb];
        #pragma unroll
        for (int rt = 0; rt < 4; ++rt) {
            int gr = r0 + rt * 16 + l15;
            short8v a = (gr < ntot) ? *(const short8v*)&A[(size_t)gr * HID + kb] : zero8();
            acc[rt][0] = __builtin_amdgcn_mfma_f32_16x16x32_bf16(a, b0, acc[rt][0], 0, 0, 0);
            acc[rt][1] = __builtin_amdgcn_mfma_f32_16x16x32_bf16(a, b1, acc[rt][1], 0, 0, 0);
        }
    }
    float bc0 = bb[cbase + l15], bc1 = bb[cbase + 16 + l15];
    #pragma unroll
    for (int rt = 0; rt < 4; ++rt)
        #pragma unroll
        for (int i = 0; i < 4; ++i) {
            int gr = r0 + rt * 16 + lg * 4 + i;
            if (gr < ntot) {
                C[(size_t)gr * HID + cbase + l15]      = f2bf1(fmaxf(acc[rt][0][i] + bc0, 0.f));
                C[(size_t)gr * HID + cbase + 16 + l15] = f2bf1(fmaxf(acc[rt][1][i] + bc1, 0.f));
            }
        }
}

// ---------------- mean pool (bf16 input): 64 rows/block ----------------
__global__ void k_pool(const unsigned short* __restrict__ x, const int* __restrict__ batch,
                       float* __restrict__ pool, int* __restrict__ cnt, int n) {
    const int ROWS = 64;
    int start = blockIdx.x * ROWS;
    if (start >= n) return;
    int end = start + ROWS; if (end > n) end = n;
    int c = threadIdx.x;
    float acc = 0.f;
    int cur = batch[start];
    int run = 0;
    for (int r = start; r < end; ++r) {
        int b = batch[r];
        if (b != cur) {
            atomicAdd(&pool[cur * HID + c], acc);
            if (c == 0) atomicAdd(&cnt[cur], run);
            acc = 0.f; run = 0; cur = b;
        }
        acc += bf2f(x[(size_t)r * HID + c]);
        run++;
    }
    atomicAdd(&pool[cur * HID + c], acc);
    if (c == 0) atomicAdd(&cnt[cur], run);
}

// ---------------- pool-div + timestep emb + combo table ----------------
__global__ void k_combo2(const int* __restrict__ t, const float* __restrict__ Wt1,
                         const float* __restrict__ bt1, const float* __restrict__ Wt2,
                         const float* __restrict__ bt2,
                         const float* __restrict__ pool, const int* __restrict__ cntb,
                         const float* __restrict__ Wn1, const float* __restrict__ bn1,
                         float* __restrict__ combo) {
    __shared__ float th[HID];
    __shared__ float pe[HID];
    __shared__ float te[HID];
    int b = blockIdx.x, c = threadIdx.x;
    float tv = (float)t[b];
    float hv = tv * Wt1[c] + bt1[c];
    th[c] = hv > 0.f ? hv : 0.f;
    float dcnt = (float)cntb[b]; if (dcnt < 1.f) dcnt = 1.f;
    pe[c] = pool[b * HID + c] / dcnt;
    __syncthreads();
    float s = bt2[c];
    for (int k = 0; k < HID; ++k) s += th[k] * Wt2[k * HID + c];
    te[c] = s;
    __syncthreads();
    const float* Wp = Wn1 + 128 * HID;
    const float* Wt = Wn1 + 256 * HID;
    float o = bn1[c];
    for (int k = 0; k < HID; ++k)
        o += pe[k] * Wp[k * HID + c] + te[k] * Wt[k * HID + c];
    combo[b * HID + c] = o;
}

// ---------------- fused final head (MFMA GEMM + epilogue + 128x3) ----------------
__global__ __launch_bounds__(256) void k_final(const unsigned short* __restrict__ A,
        const unsigned short* __restrict__ Bt /* Wn1t[0:128] */,
        const float* __restrict__ Wn1, const float* __restrict__ combo,
        const int* __restrict__ mbatch, const float* __restrict__ noisy,
        const float* __restrict__ Wn2, const float* __restrict__ bn2,
        float* __restrict__ out, int n) {
    __shared__ float hsm[64][132];
    const int tid = threadIdx.x;
    const int wid = tid >> 6;
    const int lane = tid & 63;
    const int l15 = lane & 15, lg = lane >> 4;
    const int r0 = blockIdx.x * 64;
    const int cbase = wid * 32;
    f32x4 acc[4][2] = {};
    #pragma unroll
    for (int ks = 0; ks < 4; ++ks) {
        int kb = ks * 32 + lg * 8;
        short8v b0 = *(const short8v*)&Bt[(size_t)(cbase + l15) * HID + kb];
        short8v b1 = *(const short8v*)&Bt[(size_t)(cbase + 16 + l15) * HID + kb];
        #pragma unroll
        for (int rt = 0; rt < 4; ++rt) {
            int gr = r0 + rt * 16 + l15;
            short8v a = (gr < n) ? *(const short8v*)&A[(size_t)gr * HID + kb] : zero8();
            acc[rt][0] = __builtin_amdgcn_mfma_f32_16x16x32_bf16(a, b0, acc[rt][0], 0, 0, 0);
            acc[rt][1] = __builtin_amdgcn_mfma_f32_16x16x32_bf16(a, b1, acc[rt][1], 0, 0, 0);
        }
    }
    const float* Wna = Wn1 + 384 * HID;
    #pragma unroll
    for (int rt = 0; rt < 4; ++rt)
        #pragma unroll
        for (int i = 0; i < 4; ++i) {
            int lr = rt * 16 + lg * 4 + i;
            int gr = r0 + lr;
            if (gr < n) {
                int b = mbatch[gr];
                float na0 = noisy[gr * 3 + 0], na1 = noisy[gr * 3 + 1], na2 = noisy[gr * 3 + 2];
                #pragma unroll
                for (int ct = 0; ct < 2; ++ct) {
                    int col = cbase + ct * 16 + l15;
                    float v = acc[rt][ct][i]
                            + na0 * Wna[col] + na1 * Wna[HID + col] + na2 * Wna[2 * HID + col]
                            + combo[b * HID + col];
                    hsm[lr][col] = v > 0.f ? v : 0.f;
                }
            }
        }
    __syncthreads();
    if (tid < 192) {
        int lr = tid / 3, j = tid - lr * 3;
        int gr = r0 + lr;
        if (gr < n) {
            float s = bn2[j];
            for (int c = 0; c < HID; ++c) s += hsm[lr][c] * Wn2[c * 3 + j];
            out[(size_t)gr * 3 + j] = s;
        }
    }
}

// ---------------- host ----------------
extern "C" void kernel_launch(void* const* d_in, const int* in_sizes, int n_in,
                              void* d_out, int out_size, void* d_ws, size_t ws_size,
                              hipStream_t stream) {
    const int*   p_res  = (const int*)d_in[0];
    const float* p_pos  = (const float*)d_in[1];
    const int*   p_ei   = (const int*)d_in[2];
    const int*   p_bat  = (const int*)d_in[3];
    const int*   m_res  = (const int*)d_in[4];
    const float* m_pos  = (const float*)d_in[5];
    const int*   m_ei   = (const int*)d_in[6];
    const int*   m_bat  = (const int*)d_in[7];
    const int*   t      = (const int*)d_in[8];
    const float* noisy  = (const float*)d_in[9];
    const float* Wp1 = (const float*)d_in[10], *bp1 = (const float*)d_in[11];
    const float* Wp2 = (const float*)d_in[12], *bp2 = (const float*)d_in[13];
    const float* Wm1 = (const float*)d_in[14], *bm1 = (const float*)d_in[15];
    const float* Wm2 = (const float*)d_in[16], *bm2 = (const float*)d_in[17];
    const float* Wt1 = (const float*)d_in[18], *bt1 = (const float*)d_in[19];
    const float* Wt2 = (const float*)d_in[20], *bt2 = (const float*)d_in[21];
    const float* Wn1 = (const float*)d_in[22], *bn1 = (const float*)d_in[23];
    const float* Wn2 = (const float*)d_in[24], *bn2 = (const float*)d_in[25];
    float* out = (float*)d_out;

    const int NP = in_sizes[0];
    const int EP = in_sizes[2] / 2;
    const int NM = in_sizes[4];
    const int EM = in_sizes[6] / 2;
    const int B  = in_sizes[8];
    auto al64 = [](int x) { return (x + 63) & ~63; };

    const int np64 = al64(NP);
    const long ntot_m = (long)np64 + NM;
    const long e2sum = (long)EP + EM;

    auto align256 = [](size_t x) { return (x + 255) & ~(size_t)255; };
    size_t req = 0;
    auto count = [&](size_t nb) { req = align256(req) + nb; };
    count(4ull * ntot_m);            // deg
    count(4ull * ntot_m);            // offs
    count(4ull * ntot_m);            // dinv
    count(16ull * ntot_m);           // nrec
    count(4ull * (1024 + 1025 + 1024)); // bktcnt + bofs + bcur
    count(8ull * e2sum);             // csre
    count(4ull * e2sum);             // csrs
    count(2ull * ntot_m * HID);      // hb
    count(2ull * ntot_m * HID);      // hc
    count(2ull * 3 * HID * HID);     // transposed weights
    count(4ull * (size_t)B * (HID + 1)); // pool + cntb
    count(4ull * (size_t)B * HID);   // combo
    bool merged = ws_size >= req + 4096;

    char* ws = (char*)d_ws;
    size_t off = 0;
    auto alloc = [&](size_t nb) { off = align256(off); size_t r = off; off += nb; return r; };

    const int NMAX = NP > NM ? NP : NM;
    const int EMAXs = EP > EM ? EP : EM;
    const long ntot_a = merged ? ntot_m : (long)al64(NMAX);
    const long etot_a = merged ? e2sum : (long)EMAXs;

    int*   deg  = (int*)(ws + alloc(4ull * ntot_a));
    int*   offs = (int*)(ws + alloc(4ull * ntot_a));
    float* dinv = (float*)(ws + alloc(4ull * ntot_a));
    uint4* nrec = (uint4*)(ws + alloc(16ull * ntot_a));
    int*   bktcnt = (int*)(ws + alloc(4ull * (1024 + 1025 + 1024)));
    int*   bofs = bktcnt + 1024;
    int*   bcur = bofs + 1025;
    int2*  csre = (int2*)(ws + alloc(8ull * etot_a));
    int*   csrs = (int*)(ws + alloc(4ull * etot_a));
    unsigned short* hb = (unsigned short*)(ws + alloc(2ull * ntot_a * HID));
    unsigned short* hc = (unsigned short*)(ws + alloc(2ull * ntot_a * HID));
    unsigned short* w2ta = (unsigned short*)(ws + alloc(2ull * 3 * HID * HID));
    unsigned short* w2tb = w2ta + HID * HID;
    unsigned short* wn1t = w2ta + 2 * HID * HID;
    float* pool = (float*)(ws + alloc(4ull * (size_t)B * (HID + 1)));
    int*   cntb = (int*)(pool + (size_t)B * HID);
    float* combo = (float*)(ws + alloc(4ull * (size_t)B * HID));

    k_tr<<<384, HID, 0, stream>>>(Wp2, Wm2, Wn1, w2ta, w2tb, wn1t);

    auto run = [&](int np_, int nm_,
                   const int* ei1, int e1, const int* ei2, int e2,
                   const int* res1, const float* pos1, const int* res2, const float* pos2,
                   const float* W1a, const float* b1a, const float* W1b, const float* b1b,
                   const float* b2a, const float* b2b) {
        const int np64_ = al64(np_);
        const int ntot = np64_ + nm_;
        const long etot = (long)e1 + e2;
        const int nb = (ntot + 127) >> BSH;
        const int* s1 = ei1, *d1 = ei1 + e1;
        const int* s2 = ei2, *d2 = ei2 + e2;
        hipMemsetAsync(bktcnt, 0, 4096, stream);
        k_bhist<<<(int)((etot + HCHUNK - 1) / HCHUNK), 256, 0, stream>>>(
            d1, e1, d2, e2, np64_, bktcnt, etot);
        k_bscan<<<1, 1024, 0, stream>>>(bktcnt, bofs, bcur);
        k_part<<<(int)((etot + PCHUNK - 1) / PCHUNK), 256, 0, stream>>>(
            s1, d1, e1, s2, d2, e2, np64_, bcur, csre, nb, etot);
        k_csr<<<nb, 256, 0, stream>>>(csre, bofs, csrs, deg, offs, dinv,
                                      res1, pos1, res2, pos2, np_, np64_, nrec, ntot);
        k_agg23<<<(ntot + 7) / 8, 256, 0, stream>>>(nrec, offs, deg, csrs,
                                                    np_, np64_, nm_,
                                                    W1a, b1a, W1b, b1b, (uint2*)hb);
        k_agg<<<(ntot + 7) / 8, 256, 0, stream>>>((const unsigned*)hb, offs, deg, csrs, dinv,
                                                  np_, np64_, nm_, hc);
        const int nb1 = np64_ / 64;
        const int nb2 = (nm_ + 63) / 64;
        k_gemm<<<nb1 + nb2, 256, 0, stream>>>(hc, w2ta, w2tb, b2a, b2b, nb1, np64_, ntot, hb);
    };

    if (merged) {
        run(NP, NM, p_ei, EP, m_ei, EM,
            p_res, p_pos, m_res, m_pos,
            Wp1, bp1, Wm1, bm1, bp2, bm2);
        hipMemsetAsync(pool, 0, 4ull * (size_t)B * (HID + 1), stream);
        k_pool<<<(NP + 63) / 64, HID, 0, stream>>>(hb, p_bat, pool, cntb, NP);
        k_combo2<<<B, HID, 0, stream>>>(t, Wt1, bt1, Wt2, bt2, pool, cntb, Wn1, bn1, combo);
        k_final<<<(NM + 63) / 64, 256, 0, stream>>>(hb + (size_t)np64 * HID, wn1t, Wn1, combo,
                                                    m_bat, noisy, Wn2, bn2, out, NM);
    } else {
        run(NP, 0, p_ei, EP, p_ei, 0,
            p_res, p_pos, p_res, p_pos,
            Wp1, bp1, Wp1, bp1, bp2, bp2);
        hipMemsetAsync(pool, 0, 4ull * (size_t)B * (HID + 1), stream);
        k_pool<<<(NP + 63) / 64, HID, 0, stream>>>(hb, p_bat, pool, cntb, NP);
        k_combo2<<<B, HID, 0, stream>>>(t, Wt1, bt1, Wt2, bt2, pool, cntb, Wn1, bn1, combo);
        run(0, NM, m_ei, 0, m_ei, EM,
            m_res, m_pos, m_res, m_pos,
            Wm1, bm1, Wm1, bm1, bm2, bm2);
        k_final<<<(NM + 63) / 64, 256, 0, stream>>>(hb, wn1t, Wn1, combo, m_bat, noisy,
                                                    Wn2, bn2, out, NM);
    }
}